// Round 1
// baseline (9409.684 us; speedup 1.0000x reference)
//
#include <hip/hip_runtime.h>
#include <hip/hip_bf16.h>
#include <cstdint>
#include <cstddef>

// SplineConv net: 4 layers, DIM=6, S=64 spline corners per edge.
// Strategy: bucket (edge,corner) pairs by kernel index k, then one workgroup
// per k stages W[k] in LDS and processes all pairs of that bucket (fp32 VALU),
// scatter-adding results into the per-node accumulator with atomics.

constexpr int SDIM = 6;
constexpr int SCOR = 64;   // 2^6 corners

// ---------------- degree ----------------
__global__ __launch_bounds__(256) void deg_kernel(const int* __restrict__ dst,
                                                  float* __restrict__ deg, int E) {
    int e = blockIdx.x * blockDim.x + threadIdx.x;
    if (e < E) atomicAdd(&deg[dst[e]], 1.0f);
}

// ---------------- bucketing ----------------
template <int KS>
__global__ __launch_bounds__(256) void count_kernel(const float* __restrict__ ea,
                                                    int* __restrict__ counts, int E) {
    int e = blockIdx.x * blockDim.x + threadIdx.x;
    if (e >= E) return;
    int lo[SDIM];
    #pragma unroll
    for (int d = 0; d < SDIM; d++) {
        float v = ea[e * SDIM + d] * (KS - 1);
        lo[d] = (int)floorf(v);
    }
    for (int s = 0; s < SCOR; s++) {
        int idx = 0, str = 1;
        #pragma unroll
        for (int d = 0; d < SDIM; d++) {
            int pos = lo[d] + ((s >> d) & 1);
            pos = min(max(pos, 0), KS - 1);
            idx += pos * str;
            str *= KS;
        }
        atomicAdd(&counts[idx], 1);
    }
}

template <int KS>
__global__ __launch_bounds__(256) void fill_kernel(const float* __restrict__ ea,
                                                   int* __restrict__ cursor,
                                                   int* __restrict__ pairE,
                                                   float* __restrict__ pairB, int E) {
    int e = blockIdx.x * blockDim.x + threadIdx.x;
    if (e >= E) return;
    int lo[SDIM];
    float fr[SDIM];
    #pragma unroll
    for (int d = 0; d < SDIM; d++) {
        float v = ea[e * SDIM + d] * (KS - 1);
        float fl = floorf(v);
        lo[d] = (int)fl;
        fr[d] = v - fl;
    }
    for (int s = 0; s < SCOR; s++) {
        int idx = 0, str = 1;
        float basis = 1.0f;
        #pragma unroll
        for (int d = 0; d < SDIM; d++) {
            int bit = (s >> d) & 1;
            int pos = lo[d] + bit;
            pos = min(max(pos, 0), KS - 1);
            idx += pos * str;
            str *= KS;
            basis *= bit ? fr[d] : (1.0f - fr[d]);
        }
        int slot = atomicAdd(&cursor[idx], 1);
        pairE[slot] = e;
        pairB[slot] = basis;
    }
}

// single-block exclusive scan; counts becomes the fill cursor (= offs)
__global__ __launch_bounds__(1024) void scan_kernel(int* __restrict__ counts,
                                                    int* __restrict__ offs, int K) {
    __shared__ int sums[1024];
    int t = threadIdx.x;
    int chunk = (K + 1023) / 1024;
    int a0 = t * chunk;
    int a1 = min(a0 + chunk, K);
    int s = 0;
    for (int j = a0; j < a1; j++) s += counts[j];
    sums[t] = s;
    __syncthreads();
    for (int off = 1; off < 1024; off <<= 1) {
        int v = (t >= off) ? sums[t - off] : 0;
        __syncthreads();
        sums[t] += v;
        __syncthreads();
    }
    int run = (t == 0) ? 0 : sums[t - 1];
    for (int j = a0; j < a1; j++) {
        int c = counts[j];
        offs[j] = run;
        counts[j] = run;  // cursor init for fill
        run += c;
    }
    if (t == 1023) offs[K] = run;
}

// ---------------- bucketed conv ----------------
// One block per kernel index k (grid.y chunks buckets for load balance).
// W[k] staged in LDS; each TPP-lane group handles one pair.
template <int IN, int OUT, int TPP>
__global__ __launch_bounds__(256) void bucket_conv(const float* __restrict__ x,
                                                   const int* __restrict__ src,
                                                   const int* __restrict__ dst,
                                                   const float* __restrict__ W,
                                                   const int* __restrict__ offs,
                                                   const int* __restrict__ pairE,
                                                   const float* __restrict__ pairB,
                                                   float* __restrict__ agg) {
    extern __shared__ float Wlds[];
    int k = blockIdx.x;
    int p0 = offs[k], p1 = offs[k + 1];
    if (p0 == p1) return;

    // stage W[k] (IN*OUT floats, multiple of 4)
    const float4* Wg = (const float4*)(W + (size_t)k * (IN * OUT));
    float4* Ws = (float4*)Wlds;
    for (int i = threadIdx.x; i < IN * OUT / 4; i += 256) Ws[i] = Wg[i];
    __syncthreads();

    constexpr int GROUPS = 256 / TPP;
    constexpr int R = (OUT + TPP - 1) / TPP;
    int g = threadIdx.x / TPP;
    int o = threadIdx.x % TPP;

    int start = p0 + g + blockIdx.y * GROUPS;
    int stride = GROUPS * gridDim.y;
    for (int p = start; p < p1; p += stride) {
        int e = pairE[p];
        float b = pairB[p];
        int se = src[e];
        int de = dst[e];
        const float* xr = x + (size_t)se * IN;
        float acc[R];
        #pragma unroll
        for (int r = 0; r < R; r++) acc[r] = 0.0f;
        #pragma unroll 4
        for (int i = 0; i < IN; i++) {
            float xv = xr[i];
            #pragma unroll
            for (int r = 0; r < R; r++) {
                int oo = o + r * TPP;
                if (OUT % TPP == 0 || oo < OUT)
                    acc[r] += xv * Wlds[i * OUT + oo];
            }
        }
        #pragma unroll
        for (int r = 0; r < R; r++) {
            int oo = o + r * TPP;
            if (OUT % TPP == 0 || oo < OUT)
                atomicAdd(&agg[(size_t)de * OUT + oo], b * acc[r]);
        }
    }
}

// ---------------- finalize: mean + root + bias ----------------
template <int IN, int OUT>
__global__ __launch_bounds__(256) void finalize_kernel(const float* __restrict__ agg,
                                                       const float* __restrict__ deg,
                                                       const float* __restrict__ hin,
                                                       const float* __restrict__ Wr,
                                                       const float* __restrict__ bias,
                                                       float* __restrict__ hout, int N) {
    int tid = blockIdx.x * blockDim.x + threadIdx.x;
    if (tid >= N * OUT) return;
    int n = tid / OUT;
    int o = tid % OUT;
    float d = deg[n];
    d = d < 1.0f ? 1.0f : d;
    float acc = agg[tid] / d + bias[o];
    const float* hr = hin + (size_t)n * IN;
    #pragma unroll 8
    for (int i = 0; i < IN; i++) acc += hr[i] * Wr[i * OUT + o];
    hout[tid] = acc;
}

// ---------------- ELU + log_softmax (13 classes) ----------------
__global__ __launch_bounds__(256) void head_kernel(const float* __restrict__ h,
                                                   float* __restrict__ out, int N) {
    int n = blockIdx.x * blockDim.x + threadIdx.x;
    if (n >= N) return;
    float v[13];
    float mx = -1e30f;
    #pragma unroll
    for (int c = 0; c < 13; c++) {
        float z = h[n * 13 + c];
        z = z > 0.0f ? z : (expf(z) - 1.0f);
        v[c] = z;
        mx = fmaxf(mx, z);
    }
    float sum = 0.0f;
    #pragma unroll
    for (int c = 0; c < 13; c++) sum += expf(v[c] - mx);
    float lse = mx + logf(sum);
    #pragma unroll
    for (int c = 0; c < 13; c++) out[n * 13 + c] = v[c] - lse;
}

extern "C" void kernel_launch(void* const* d_in, const int* in_sizes, int n_in,
                              void* d_out, int out_size, void* d_ws, size_t ws_size,
                              hipStream_t stream) {
    const float* x   = (const float*)d_in[0];
    const int*   ei  = (const int*)d_in[1];
    const float* ea  = (const float*)d_in[2];
    const float* W1  = (const float*)d_in[3];
    const float* Wr1 = (const float*)d_in[4];
    const float* b1  = (const float*)d_in[5];
    const float* W3  = (const float*)d_in[6];
    const float* Wr3 = (const float*)d_in[7];
    const float* b3  = (const float*)d_in[8];
    const float* W6  = (const float*)d_in[9];
    const float* Wr6 = (const float*)d_in[10];
    const float* b6  = (const float*)d_in[11];
    const float* W7  = (const float*)d_in[12];
    const float* Wr7 = (const float*)d_in[13];
    const float* b7  = (const float*)d_in[14];

    const int N = in_sizes[0] / 32;
    const int E = in_sizes[1] / 2;
    const int* src = ei;
    const int* dst = ei + E;
    const int P = E * SCOR;
    (void)P; (void)n_in; (void)out_size; (void)ws_size;

    const int K3 = 729, K5 = 15625, K7 = 117649;

    char* ws = (char*)d_ws;
    size_t off = 0;
    auto alloc = [&](size_t bytes) {
        void* p = ws + off;
        off += (bytes + 255) & ~(size_t)255;
        return p;
    };
    float* deg   = (float*)alloc((size_t)N * 4);
    float* h1    = (float*)alloc((size_t)N * 128 * 4);
    float* h3    = (float*)alloc((size_t)N * 128 * 4);
    float* h6    = (float*)alloc((size_t)N * 64 * 4);
    float* h7    = (float*)alloc((size_t)N * 13 * 4);
    float* agg   = (float*)alloc((size_t)N * 128 * 4);
    int*   cnt   = (int*)alloc((size_t)K7 * 4);
    int*   offsb = (int*)alloc((size_t)(K7 + 1) * 4);
    int*   pairE = (int*)alloc((size_t)E * SCOR * 4);
    float* pairB = (float*)alloc((size_t)E * SCOR * 4);

    dim3 blk(256);
    dim3 egrid((E + 255) / 256);

    // degree (same for all layers)
    hipMemsetAsync(deg, 0, (size_t)N * 4, stream);
    deg_kernel<<<egrid, blk, 0, stream>>>(dst, deg, E);

    // ---- ks=3 buckets (shared by layers 1 and 3) ----
    hipMemsetAsync(cnt, 0, (size_t)K3 * 4, stream);
    count_kernel<3><<<egrid, blk, 0, stream>>>(ea, cnt, E);
    scan_kernel<<<1, 1024, 0, stream>>>(cnt, offsb, K3);
    fill_kernel<3><<<egrid, blk, 0, stream>>>(ea, cnt, pairE, pairB, E);

    // layer 1: 32 -> 128
    hipMemsetAsync(agg, 0, (size_t)N * 128 * 4, stream);
    bucket_conv<32, 128, 64><<<dim3(K3, 8), blk, 32 * 128 * 4, stream>>>(
        x, src, dst, W1, offsb, pairE, pairB, agg);
    finalize_kernel<32, 128><<<(N * 128 + 255) / 256, blk, 0, stream>>>(
        agg, deg, x, Wr1, b1, h1, N);

    // layer 3: 128 -> 128
    hipMemsetAsync(agg, 0, (size_t)N * 128 * 4, stream);
    bucket_conv<128, 128, 64><<<dim3(K3, 8), blk, 128 * 128 * 4, stream>>>(
        h1, src, dst, W3, offsb, pairE, pairB, agg);
    finalize_kernel<128, 128><<<(N * 128 + 255) / 256, blk, 0, stream>>>(
        agg, deg, h1, Wr3, b3, h3, N);

    // ---- ks=5 buckets ----
    hipMemsetAsync(cnt, 0, (size_t)K5 * 4, stream);
    count_kernel<5><<<egrid, blk, 0, stream>>>(ea, cnt, E);
    scan_kernel<<<1, 1024, 0, stream>>>(cnt, offsb, K5);
    fill_kernel<5><<<egrid, blk, 0, stream>>>(ea, cnt, pairE, pairB, E);

    // layer 6: 128 -> 64
    hipMemsetAsync(agg, 0, (size_t)N * 64 * 4, stream);
    bucket_conv<128, 64, 64><<<dim3(K5, 1), blk, 128 * 64 * 4, stream>>>(
        h3, src, dst, W6, offsb, pairE, pairB, agg);
    finalize_kernel<128, 64><<<(N * 64 + 255) / 256, blk, 0, stream>>>(
        agg, deg, h3, Wr6, b6, h6, N);

    // ---- ks=7 buckets ----
    hipMemsetAsync(cnt, 0, (size_t)K7 * 4, stream);
    count_kernel<7><<<egrid, blk, 0, stream>>>(ea, cnt, E);
    scan_kernel<<<1, 1024, 0, stream>>>(cnt, offsb, K7);
    fill_kernel<7><<<egrid, blk, 0, stream>>>(ea, cnt, pairE, pairB, E);

    // layer 7: 64 -> 13
    hipMemsetAsync(agg, 0, (size_t)N * 13 * 4, stream);
    bucket_conv<64, 13, 16><<<dim3(K7, 1), blk, 64 * 13 * 4, stream>>>(
        h6, src, dst, W7, offsb, pairE, pairB, agg);
    finalize_kernel<64, 13><<<(N * 13 + 255) / 256, blk, 0, stream>>>(
        agg, deg, h6, Wr7, b7, h7, N);

    // ELU + log_softmax
    head_kernel<<<(N + 255) / 256, blk, 0, stream>>>(h7, (float*)d_out, N);
}

// Round 2
// 4006.886 us; speedup vs baseline: 2.3484x; 2.3484x over previous
//
#include <hip/hip_runtime.h>
#include <hip/hip_bf16.h>
#include <cstdint>
#include <cstddef>

constexpr int SDIM = 6;
constexpr int SCOR = 64;   // 2^6 corners
typedef unsigned short u16;

__device__ __forceinline__ float bf2f(u16 h) {
    union { unsigned u; float f; } v; v.u = ((unsigned)h) << 16; return v.f;
}
__device__ __forceinline__ u16 f2bf(float f) {
    union { float f; unsigned u; } v; v.f = f;
    unsigned r = v.u + 0x7fffu + ((v.u >> 16) & 1u);
    return (u16)(r >> 16);
}

// ---------------- degree (int counts) ----------------
__global__ __launch_bounds__(256) void deg_kernel(const int* __restrict__ dst,
                                                  int* __restrict__ degi, int E) {
    int e = blockIdx.x * blockDim.x + threadIdx.x;
    if (e < E) atomicAdd(&degi[dst[e]], 1);
}

// erank: absolute dst-sorted slot per edge. cursor = degi after scan (holds start offsets).
__global__ __launch_bounds__(256) void erank_kernel(const int* __restrict__ dst,
                                                    int* __restrict__ cursor,
                                                    int* __restrict__ erank, int E) {
    int e = blockIdx.x * blockDim.x + threadIdx.x;
    if (e < E) erank[e] = atomicAdd(&cursor[dst[e]], 1);
}

// ---------------- bucketing ----------------
template <int KS>
__global__ __launch_bounds__(256) void count_kernel(const float* __restrict__ ea,
                                                    int* __restrict__ counts, int E) {
    int e = blockIdx.x * blockDim.x + threadIdx.x;
    if (e >= E) return;
    int lo[SDIM];
    #pragma unroll
    for (int d = 0; d < SDIM; d++) {
        float v = ea[e * SDIM + d] * (KS - 1);
        lo[d] = (int)floorf(v);
    }
    for (int s = 0; s < SCOR; s++) {
        int idx = 0, str = 1;
        #pragma unroll
        for (int d = 0; d < SDIM; d++) {
            int pos = lo[d] + ((s >> d) & 1);
            pos = min(max(pos, 0), KS - 1);
            idx += pos * str;
            str *= KS;
        }
        atomicAdd(&counts[idx], 1);
    }
}

template <int KS>
__global__ __launch_bounds__(256) void fill_kernel(const float* __restrict__ ea,
                                                   int* __restrict__ cursor,
                                                   const int* __restrict__ erank,
                                                   int* __restrict__ pairE,
                                                   float* __restrict__ pairB,
                                                   int* __restrict__ pairO, int E) {
    int e = blockIdx.x * blockDim.x + threadIdx.x;
    if (e >= E) return;
    int lo[SDIM];
    float fr[SDIM];
    #pragma unroll
    for (int d = 0; d < SDIM; d++) {
        float v = ea[e * SDIM + d] * (KS - 1);
        float fl = floorf(v);
        lo[d] = (int)fl;
        fr[d] = v - fl;
    }
    int er = erank[e] * SCOR;
    for (int s = 0; s < SCOR; s++) {
        int idx = 0, str = 1;
        float basis = 1.0f;
        #pragma unroll
        for (int d = 0; d < SDIM; d++) {
            int bit = (s >> d) & 1;
            int pos = lo[d] + bit;
            pos = min(max(pos, 0), KS - 1);
            idx += pos * str;
            str *= KS;
            basis *= bit ? fr[d] : (1.0f - fr[d]);
        }
        int slot = atomicAdd(&cursor[idx], 1);
        pairE[slot] = e;
        pairB[slot] = basis;
        pairO[slot] = er + s;
    }
}

// single-block exclusive scan; counts becomes the fill cursor (= offs)
__global__ __launch_bounds__(1024) void scan_kernel(int* __restrict__ counts,
                                                    int* __restrict__ offs, int K) {
    __shared__ int sums[1024];
    int t = threadIdx.x;
    int chunk = (K + 1023) / 1024;
    int a0 = t * chunk;
    int a1 = min(a0 + chunk, K);
    int s = 0;
    for (int j = a0; j < a1; j++) s += counts[j];
    sums[t] = s;
    __syncthreads();
    for (int off = 1; off < 1024; off <<= 1) {
        int v = (t >= off) ? sums[t - off] : 0;
        __syncthreads();
        sums[t] += v;
        __syncthreads();
    }
    int run = (t == 0) ? 0 : sums[t - 1];
    for (int j = a0; j < a1; j++) {
        int c = counts[j];
        offs[j] = run;
        counts[j] = run;  // cursor init
        run += c;
    }
    if (t == 1023) offs[K] = run;
}

// ---------------- tiled bucketed conv ----------------
// grid (K, GY). Block stages W[k] in LDS (bf16 if WBF), x-tile transposed in LDS.
// Thread tile: RP pairs x 4 outs in fp32 registers.
// Epilogue: non-atomic -> bf16 row store to mpart[pairO[p]]; atomic -> agg scatter.
template <int IN, int OUT, int OUTP, int TP, bool WBF, bool ATOMIC>
__global__ __launch_bounds__(256) void conv_kernel(
    const float* __restrict__ x, const int* __restrict__ src,
    const int* __restrict__ dst, const float* __restrict__ W,
    const int* __restrict__ offs, const int* __restrict__ pairE,
    const float* __restrict__ pairB, const int* __restrict__ pairO,
    u16* __restrict__ mpart, float* __restrict__ agg) {
    int k = blockIdx.x;
    int p0 = offs[k], p1 = offs[k + 1];
    if (p0 + TP * (int)blockIdx.y >= p1) return;

    extern __shared__ char lds[];
    constexpr int WBYTES = IN * OUTP * (WBF ? 2 : 4);
    float* xT = (float*)(lds + WBYTES);
    int* sE = (int*)(lds + WBYTES + IN * TP * 4);
    const int t = threadIdx.x;

    // ---- stage W[k] ----
    if constexpr (WBF) {
        const float4* Wg = (const float4*)(W + (size_t)k * IN * OUT);
        u16* Ws = (u16*)lds;
        for (int f = t; f < IN * OUT / 4; f += 256) {
            float4 v = Wg[f];
            Ws[4 * f + 0] = f2bf(v.x);
            Ws[4 * f + 1] = f2bf(v.y);
            Ws[4 * f + 2] = f2bf(v.z);
            Ws[4 * f + 3] = f2bf(v.w);
        }
    } else if constexpr (OUTP == OUT) {
        const float4* Wg = (const float4*)(W + (size_t)k * IN * OUT);
        float4* Ws = (float4*)lds;
        for (int f = t; f < IN * OUT / 4; f += 256) Ws[f] = Wg[f];
    } else {
        float* Ws = (float*)lds;
        for (int f = t; f < IN * OUTP; f += 256) Ws[f] = 0.0f;
        __syncthreads();
        const float* Wg = W + (size_t)k * IN * OUT;
        for (int f = t; f < IN * OUT; f += 256)
            Ws[(f / OUT) * OUTP + (f % OUT)] = Wg[f];
    }

    constexpr int OG = OUTP / 4;   // out-groups of 4
    constexpr int PG = 256 / OG;   // pair-groups
    constexpr int RP = TP / PG;    // pairs per thread
    static_assert(RP * PG == TP, "tile mismatch");
    int og = t % OG, pg = t / OG;

    for (int t0 = p0 + TP * blockIdx.y; t0 < p1; t0 += TP * gridDim.y) {
        int np = min(TP, p1 - t0);
        __syncthreads();   // protect LDS from previous tile's readers
        if (t < np) sE[t] = src[pairE[t0 + t]];
        __syncthreads();
        // stage x tile transposed: xT[i][j]
        for (int f = t; f < (IN / 4) * TP; f += 256) {
            int j = f % TP, i4 = f / TP;
            if (j < np) {
                float4 v = ((const float4*)(x + (size_t)sE[j] * IN))[i4];
                xT[(4 * i4 + 0) * TP + j] = v.x;
                xT[(4 * i4 + 1) * TP + j] = v.y;
                xT[(4 * i4 + 2) * TP + j] = v.z;
                xT[(4 * i4 + 3) * TP + j] = v.w;
            }
        }
        __syncthreads();

        float acc[RP][4];
        #pragma unroll
        for (int r = 0; r < RP; r++)
            acc[r][0] = acc[r][1] = acc[r][2] = acc[r][3] = 0.0f;

        #pragma unroll 4
        for (int i = 0; i < IN; i++) {
            float wv[4];
            if constexpr (WBF) {
                ushort4 wr = ((const ushort4*)lds)[i * OG + og];
                wv[0] = bf2f(wr.x); wv[1] = bf2f(wr.y);
                wv[2] = bf2f(wr.z); wv[3] = bf2f(wr.w);
            } else {
                float4 w4 = ((const float4*)lds)[i * OG + og];
                wv[0] = w4.x; wv[1] = w4.y; wv[2] = w4.z; wv[3] = w4.w;
            }
            float xa[RP];
            if constexpr (RP == 4) {
                float4 xv = *(const float4*)&xT[i * TP + pg * 4];
                xa[0] = xv.x; xa[1] = xv.y; xa[2] = xv.z; xa[3] = xv.w;
            } else if constexpr (RP == 2) {
                float2 xv = *(const float2*)&xT[i * TP + pg * 2];
                xa[0] = xv.x; xa[1] = xv.y;
            } else {
                xa[0] = xT[i * TP + pg];
            }
            #pragma unroll
            for (int r = 0; r < RP; r++)
                #pragma unroll
                for (int c = 0; c < 4; c++) acc[r][c] += xa[r] * wv[c];
        }

        // epilogue
        #pragma unroll
        for (int r = 0; r < RP; r++) {
            int pl = pg * RP + r;
            if (pl < np) {
                int p = t0 + pl;
                float b = pairB[p];
                if constexpr (ATOMIC) {
                    int de = dst[pairE[p]];
                    float* ap = agg + (size_t)de * OUT + og * 4;
                    #pragma unroll
                    for (int c = 0; c < 4; c++)
                        if (OUTP == OUT || og * 4 + c < OUT)
                            atomicAdd(ap + c, b * acc[r][c]);
                } else {
                    size_t row = (size_t)pairO[p];
                    u16* mp = mpart + row * OUTP + og * 4;
                    ushort4 pk;
                    pk.x = f2bf(b * acc[r][0]);
                    pk.y = f2bf(b * acc[r][1]);
                    pk.z = f2bf(b * acc[r][2]);
                    pk.w = f2bf(b * acc[r][3]);
                    *(ushort4*)mp = pk;
                }
            }
        }
    }
}

// ---------------- segment reduce + mean + root + bias ----------------
template <int IN, int OUT, int OUTP>
__global__ __launch_bounds__(256) void reduce_kernel(
    const u16* __restrict__ mpart, const int* __restrict__ eoff,
    const float* __restrict__ xin, const float* __restrict__ Wr,
    const float* __restrict__ bias, float* __restrict__ hout, int N) {
    int n = blockIdx.x;
    int e0 = eoff[n], e1 = eoff[n + 1];
    int deg = e1 - e0;
    size_t rs = (size_t)e0 * SCOR;
    int R = deg * SCOR;
    constexpr int OG = OUTP / 4;
    constexpr int G = 256 / OG;
    int t = threadIdx.x;
    int og = t % OG, rg = t / OG;
    float a[4] = {0.f, 0.f, 0.f, 0.f};
    for (int r = rg; r < R; r += G) {
        ushort4 v = ((const ushort4*)(mpart + (rs + r) * OUTP))[og];
        a[0] += bf2f(v.x); a[1] += bf2f(v.y); a[2] += bf2f(v.z); a[3] += bf2f(v.w);
    }
    __shared__ float part[256 * 4];
    part[t * 4 + 0] = a[0]; part[t * 4 + 1] = a[1];
    part[t * 4 + 2] = a[2]; part[t * 4 + 3] = a[3];
    __syncthreads();
    if (t < OUTP && t < OUT) {
        float s = 0.f;
        for (int g = 0; g < G; g++) s += part[(g * OG + t / 4) * 4 + (t % 4)];
        float d = deg < 1 ? 1.0f : (float)deg;
        s /= d;
        s += bias[t];
        const float* xr = xin + (size_t)n * IN;
        #pragma unroll 8
        for (int i = 0; i < IN; i++) s += xr[i] * Wr[i * OUT + t];
        hout[(size_t)n * OUT + t] = s;
    }
}

// ---------------- fallback finalize (atomic path) ----------------
template <int IN, int OUT>
__global__ __launch_bounds__(256) void finalize_kernel(const float* __restrict__ agg,
                                                       const int* __restrict__ eoff,
                                                       const float* __restrict__ hin,
                                                       const float* __restrict__ Wr,
                                                       const float* __restrict__ bias,
                                                       float* __restrict__ hout, int N) {
    int tid = blockIdx.x * blockDim.x + threadIdx.x;
    if (tid >= N * OUT) return;
    int n = tid / OUT;
    int o = tid % OUT;
    int dg = eoff[n + 1] - eoff[n];
    float d = dg < 1 ? 1.0f : (float)dg;
    float acc = agg[tid] / d + bias[o];
    const float* hr = hin + (size_t)n * IN;
    #pragma unroll 8
    for (int i = 0; i < IN; i++) acc += hr[i] * Wr[i * OUT + o];
    hout[tid] = acc;
}

// ---------------- ELU + log_softmax (13 classes) ----------------
__global__ __launch_bounds__(256) void head_kernel(const float* __restrict__ h,
                                                   float* __restrict__ out, int N) {
    int n = blockIdx.x * blockDim.x + threadIdx.x;
    if (n >= N) return;
    float v[13];
    float mx = -1e30f;
    #pragma unroll
    for (int c = 0; c < 13; c++) {
        float z = h[n * 13 + c];
        z = z > 0.0f ? z : (expf(z) - 1.0f);
        v[c] = z;
        mx = fmaxf(mx, z);
    }
    float sum = 0.0f;
    #pragma unroll
    for (int c = 0; c < 13; c++) sum += expf(v[c] - mx);
    float lse = mx + logf(sum);
    #pragma unroll
    for (int c = 0; c < 13; c++) out[n * 13 + c] = v[c] - lse;
}

extern "C" void kernel_launch(void* const* d_in, const int* in_sizes, int n_in,
                              void* d_out, int out_size, void* d_ws, size_t ws_size,
                              hipStream_t stream) {
    const float* x   = (const float*)d_in[0];
    const int*   ei  = (const int*)d_in[1];
    const float* ea  = (const float*)d_in[2];
    const float* W1  = (const float*)d_in[3];
    const float* Wr1 = (const float*)d_in[4];
    const float* b1  = (const float*)d_in[5];
    const float* W3  = (const float*)d_in[6];
    const float* Wr3 = (const float*)d_in[7];
    const float* b3  = (const float*)d_in[8];
    const float* W6  = (const float*)d_in[9];
    const float* Wr6 = (const float*)d_in[10];
    const float* b6  = (const float*)d_in[11];
    const float* W7  = (const float*)d_in[12];
    const float* Wr7 = (const float*)d_in[13];
    const float* b7  = (const float*)d_in[14];

    const int N = in_sizes[0] / 32;
    const int E = in_sizes[1] / 2;
    const int* src = ei;
    const int* dst = ei + E;
    (void)n_in; (void)out_size;

    const int K3 = 729, K5 = 15625, K7 = 117649;

    char* ws = (char*)d_ws;
    size_t off = 0;
    auto alloc = [&](size_t bytes) {
        void* p = ws + off;
        off += (bytes + 255) & ~(size_t)255;
        return p;
    };
    int*   degi  = (int*)alloc((size_t)N * 4);
    int*   eoff  = (int*)alloc((size_t)(N + 1) * 4);
    int*   erank = (int*)alloc((size_t)E * 4);
    int*   cnt   = (int*)alloc((size_t)K7 * 4);
    int*   offsb = (int*)alloc((size_t)(K7 + 1) * 4);
    int*   pairE = (int*)alloc((size_t)E * SCOR * 4);
    float* pairB = (float*)alloc((size_t)E * SCOR * 4);
    int*   pairO = (int*)alloc((size_t)E * SCOR * 4);
    float* h1    = (float*)alloc((size_t)N * 128 * 4);
    float* h3    = (float*)alloc((size_t)N * 128 * 4);
    float* h6    = (float*)alloc((size_t)N * 64 * 4);
    float* h7    = (float*)alloc((size_t)N * 13 * 4);
    float* agg   = (float*)alloc((size_t)N * 128 * 4);
    size_t mpart_bytes = (size_t)E * SCOR * 128 * 2;  // 256 MiB (max OUTP)
    u16*   mpart = (u16*)alloc(mpart_bytes);
    const bool FULL = ws_size >= off;   // enough scratch for the mpart path?

    dim3 blk(256);
    dim3 egrid((E + 255) / 256);

    // ---- degree / dst-sorted edge ranks ----
    hipMemsetAsync(degi, 0, (size_t)N * 4, stream);
    deg_kernel<<<egrid, blk, 0, stream>>>(dst, degi, E);
    scan_kernel<<<1, 1024, 0, stream>>>(degi, eoff, N);   // degi -> cursor
    erank_kernel<<<egrid, blk, 0, stream>>>(dst, degi, erank, E);

    // ---- ks=3 buckets (layers 1 & 3) ----
    hipMemsetAsync(cnt, 0, (size_t)K3 * 4, stream);
    count_kernel<3><<<egrid, blk, 0, stream>>>(ea, cnt, E);
    scan_kernel<<<1, 1024, 0, stream>>>(cnt, offsb, K3);
    fill_kernel<3><<<egrid, blk, 0, stream>>>(ea, cnt, erank, pairE, pairB, pairO, E);

    // layer 1: 32 -> 128
    if (FULL) {
        conv_kernel<32, 128, 128, 32, false, false><<<dim3(K3, 16), blk, 20608, stream>>>(
            x, src, dst, W1, offsb, pairE, pairB, pairO, mpart, nullptr);
        reduce_kernel<32, 128, 128><<<N, blk, 0, stream>>>(mpart, eoff, x, Wr1, b1, h1, N);
    } else {
        hipMemsetAsync(agg, 0, (size_t)N * 128 * 4, stream);
        conv_kernel<32, 128, 128, 32, false, true><<<dim3(K3, 16), blk, 20608, stream>>>(
            x, src, dst, W1, offsb, pairE, pairB, pairO, nullptr, agg);
        finalize_kernel<32, 128><<<(N * 128 + 255) / 256, blk, 0, stream>>>(
            agg, eoff, x, Wr1, b1, h1, N);
    }

    // layer 3: 128 -> 128 (bf16 W in LDS to fit 64 KB)
    if (FULL) {
        conv_kernel<128, 128, 128, 32, true, false><<<dim3(K3, 32), blk, 49280, stream>>>(
            h1, src, dst, W3, offsb, pairE, pairB, pairO, mpart, nullptr);
        reduce_kernel<128, 128, 128><<<N, blk, 0, stream>>>(mpart, eoff, h1, Wr3, b3, h3, N);
    } else {
        hipMemsetAsync(agg, 0, (size_t)N * 128 * 4, stream);
        conv_kernel<128, 128, 128, 32, true, true><<<dim3(K3, 32), blk, 49280, stream>>>(
            h1, src, dst, W3, offsb, pairE, pairB, pairO, nullptr, agg);
        finalize_kernel<128, 128><<<(N * 128 + 255) / 256, blk, 0, stream>>>(
            agg, eoff, h1, Wr3, b3, h3, N);
    }

    // ---- ks=5 buckets ----
    hipMemsetAsync(cnt, 0, (size_t)K5 * 4, stream);
    count_kernel<5><<<egrid, blk, 0, stream>>>(ea, cnt, E);
    scan_kernel<<<1, 1024, 0, stream>>>(cnt, offsb, K5);
    fill_kernel<5><<<egrid, blk, 0, stream>>>(ea, cnt, erank, pairE, pairB, pairO, E);

    // layer 6: 128 -> 64
    if (FULL) {
        conv_kernel<128, 64, 64, 64, true, false><<<dim3(K5, 1), blk, 49408, stream>>>(
            h3, src, dst, W6, offsb, pairE, pairB, pairO, mpart, nullptr);
        reduce_kernel<128, 64, 64><<<N, blk, 0, stream>>>(mpart, eoff, h3, Wr6, b6, h6, N);
    } else {
        hipMemsetAsync(agg, 0, (size_t)N * 64 * 4, stream);
        conv_kernel<128, 64, 64, 64, true, true><<<dim3(K5, 1), blk, 49408, stream>>>(
            h3, src, dst, W6, offsb, pairE, pairB, pairO, nullptr, agg);
        finalize_kernel<128, 64><<<(N * 64 + 255) / 256, blk, 0, stream>>>(
            agg, eoff, h3, Wr6, b6, h6, N);
    }

    // ---- ks=7 buckets ----
    hipMemsetAsync(cnt, 0, (size_t)K7 * 4, stream);
    count_kernel<7><<<egrid, blk, 0, stream>>>(ea, cnt, E);
    scan_kernel<<<1, 1024, 0, stream>>>(cnt, offsb, K7);
    fill_kernel<7><<<egrid, blk, 0, stream>>>(ea, cnt, erank, pairE, pairB, pairO, E);

    // layer 7: 64 -> 13 (padded to 16)
    if (FULL) {
        conv_kernel<64, 13, 16, 64, false, false><<<dim3(K7, 1), blk, 20736, stream>>>(
            h6, src, dst, W7, offsb, pairE, pairB, pairO, mpart, nullptr);
        reduce_kernel<64, 13, 16><<<N, blk, 0, stream>>>(mpart, eoff, h6, Wr7, b7, h7, N);
    } else {
        hipMemsetAsync(agg, 0, (size_t)N * 13 * 4, stream);
        conv_kernel<64, 13, 16, 64, false, true><<<dim3(K7, 1), blk, 20736, stream>>>(
            h6, src, dst, W7, offsb, pairE, pairB, pairO, nullptr, agg);
        finalize_kernel<64, 13><<<(N * 13 + 255) / 256, blk, 0, stream>>>(
            agg, eoff, h6, Wr7, b7, h7, N);
    }

    // ELU + log_softmax
    head_kernel<<<(N + 255) / 256, blk, 0, stream>>>(h7, (float*)d_out, N);
}

// Round 3
// 2885.122 us; speedup vs baseline: 3.2615x; 1.3888x over previous
//
#include <hip/hip_runtime.h>
#include <hip/hip_bf16.h>
#include <cstdint>
#include <cstddef>

constexpr int SDIM = 6;
constexpr int SCOR = 64;   // 2^6 corners
typedef unsigned short u16;
typedef __attribute__((ext_vector_type(8))) short bf16x8;
typedef __attribute__((ext_vector_type(4))) float f32x4;

__device__ __forceinline__ float bf2f(u16 h) {
    union { unsigned u; float f; } v; v.u = ((unsigned)h) << 16; return v.f;
}
__device__ __forceinline__ u16 f2bf(float f) {
    union { float f; unsigned u; } v; v.f = f;
    unsigned r = v.u + 0x7fffu + ((v.u >> 16) & 1u);
    return (u16)(r >> 16);
}

// ---------------- fp32 -> bf16 convert ----------------
__global__ __launch_bounds__(256) void tobf_kernel(const float* __restrict__ in,
                                                   u16* __restrict__ out, int n4) {
    int i = blockIdx.x * blockDim.x + threadIdx.x;
    if (i < n4) {
        float4 v = ((const float4*)in)[i];
        ushort4 o;
        o.x = f2bf(v.x); o.y = f2bf(v.y); o.z = f2bf(v.z); o.w = f2bf(v.w);
        ((ushort4*)out)[i] = o;
    }
}

// ---------------- degree ----------------
__global__ __launch_bounds__(256) void deg_kernel(const int* __restrict__ dst,
                                                  int* __restrict__ degi, int E) {
    int e = blockIdx.x * blockDim.x + threadIdx.x;
    if (e < E) atomicAdd(&degi[dst[e]], 1);
}

__global__ __launch_bounds__(256) void erank_kernel(const int* __restrict__ dst,
                                                    int* __restrict__ cursor,
                                                    int* __restrict__ erank, int E) {
    int e = blockIdx.x * blockDim.x + threadIdx.x;
    if (e < E) erank[e] = atomicAdd(&cursor[dst[e]], 1);
}

// ---------------- bucketing ----------------
template <int KS>
__global__ __launch_bounds__(256) void count_kernel(const float* __restrict__ ea,
                                                    int* __restrict__ counts, int E) {
    int e = blockIdx.x * blockDim.x + threadIdx.x;
    if (e >= E) return;
    int lo[SDIM];
    #pragma unroll
    for (int d = 0; d < SDIM; d++) {
        float v = ea[e * SDIM + d] * (KS - 1);
        lo[d] = (int)floorf(v);
    }
    for (int s = 0; s < SCOR; s++) {
        int idx = 0, str = 1;
        #pragma unroll
        for (int d = 0; d < SDIM; d++) {
            int pos = lo[d] + ((s >> d) & 1);
            pos = min(max(pos, 0), KS - 1);
            idx += pos * str;
            str *= KS;
        }
        atomicAdd(&counts[idx], 1);
    }
}

// fill: slot -> (edge, basis); perm: dst-sorted pair index -> slot
template <int KS>
__global__ __launch_bounds__(256) void fill_kernel(const float* __restrict__ ea,
                                                   int* __restrict__ cursor,
                                                   const int* __restrict__ erank,
                                                   int* __restrict__ pairE,
                                                   float* __restrict__ pairB,
                                                   int* __restrict__ perm, int E) {
    int e = blockIdx.x * blockDim.x + threadIdx.x;
    if (e >= E) return;
    int lo[SDIM];
    float fr[SDIM];
    #pragma unroll
    for (int d = 0; d < SDIM; d++) {
        float v = ea[e * SDIM + d] * (KS - 1);
        float fl = floorf(v);
        lo[d] = (int)fl;
        fr[d] = v - fl;
    }
    int er = erank[e] * SCOR;
    for (int s = 0; s < SCOR; s++) {
        int idx = 0, str = 1;
        float basis = 1.0f;
        #pragma unroll
        for (int d = 0; d < SDIM; d++) {
            int bit = (s >> d) & 1;
            int pos = lo[d] + bit;
            pos = min(max(pos, 0), KS - 1);
            idx += pos * str;
            str *= KS;
            basis *= bit ? fr[d] : (1.0f - fr[d]);
        }
        int slot = atomicAdd(&cursor[idx], 1);
        pairE[slot] = e;
        pairB[slot] = basis;
        perm[er + s] = slot;
    }
}

// single-block exclusive scan; counts becomes the fill cursor (= offs)
__global__ __launch_bounds__(1024) void scan_kernel(int* __restrict__ counts,
                                                    int* __restrict__ offs, int K) {
    __shared__ int sums[1024];
    int t = threadIdx.x;
    int chunk = (K + 1023) / 1024;
    int a0 = t * chunk;
    int a1 = min(a0 + chunk, K);
    int s = 0;
    for (int j = a0; j < a1; j++) s += counts[j];
    sums[t] = s;
    __syncthreads();
    for (int off = 1; off < 1024; off <<= 1) {
        int v = (t >= off) ? sums[t - off] : 0;
        __syncthreads();
        sums[t] += v;
        __syncthreads();
    }
    int run = (t == 0) ? 0 : sums[t - 1];
    for (int j = a0; j < a1; j++) {
        int c = counts[j];
        offs[j] = run;
        counts[j] = run;  // cursor init
        run += c;
    }
    if (t == 1023) offs[K] = run;
}

// ---------------- MFMA bucketed conv ----------------
// One bucket k per blockIdx.x, tiles split over blockIdx.y (GY).
// W[k] staged fp32->bf16 in LDS in MFMA B-fragment order (linear ds_read_b128).
// A fragments gathered directly from bf16 x rows (L2 resident).
// C fragments scaled by basis, transposed through LDS, stored coalesced to
// mpart in bucket-slot order.
template <int IN, int OUT, int WM, int WN, int GY>
__global__ __launch_bounds__(256) void conv_mfma(
    const u16* __restrict__ xbf, const int* __restrict__ src,
    const float* __restrict__ W, const int* __restrict__ offs,
    const int* __restrict__ pairE, const float* __restrict__ pairB,
    u16* __restrict__ mpart) {
    constexpr int OUT16 = (OUT + 15) & ~15;
    constexpr int NF = OUT16 / 16;   // total col-frags
    constexpr int NFW = NF / WN;     // col-frags per wave
    constexpr int MT = WM * 16;      // pairs per tile
    constexpr int KS = IN / 32;      // k-steps
    constexpr int STR = OUT16 + 8;   // tbuf stride (u16), keeps 16B align + bank spread
    constexpr int CH = OUT16 / 8;    // 16B chunks per row

    extern __shared__ char lds[];
    u16* Wf = (u16*)lds;                                     // IN*OUT16
    u16* tbuf = (u16*)(lds + IN * OUT16 * 2);                // MT*STR
    int* sE = (int*)(lds + IN * OUT16 * 2 + MT * STR * 2);   // MT
    float* bas = (float*)(sE + MT);                          // MT

    int k = blockIdx.x;
    int p0 = offs[k], p1 = offs[k + 1];
    if (p0 + MT * (int)blockIdx.y >= p1) return;

    int t = threadIdx.x;
    // stage W[k]: fp32 row-major [IN][OUT] -> bf16 fragment order
    const float* Wg = W + (size_t)k * IN * OUT;
    for (int f = t; f < IN * OUT16; f += 256) {
        int i = f / OUT16, o = f % OUT16;
        float v = (OUT == OUT16 || o < OUT) ? Wg[i * OUT + o] : 0.0f;
        int ks = i >> 5, koct = (i >> 3) & 3, j = i & 7, nf = o >> 4, c = o & 15;
        Wf[(((ks * NF + nf) * 16 + c) << 5) + (koct << 3) + j] = f2bf(v);
    }
    __syncthreads();

    int wid = t >> 6, lane = t & 63;
    int wm = wid % WM, wn = wid / WM;
    int l15 = lane & 15, l4 = lane >> 4;

    for (int t0 = p0 + MT * blockIdx.y; t0 < p1; t0 += MT * GY) {
        int np = min(MT, p1 - t0);
        if (t < MT) {
            int pp = t0 + t;
            sE[t] = (pp < p1) ? src[pairE[pp]] : 0;
            bas[t] = (pp < p1) ? pairB[pp] : 0.0f;
        }
        __syncthreads();

        int prow = wm * 16 + l15;
        int node = sE[prow < np ? prow : 0];
        const u16* xrow = xbf + (size_t)node * IN + l4 * 8;

        f32x4 acc[NFW];
        #pragma unroll
        for (int nf = 0; nf < NFW; nf++)
            acc[nf] = f32x4{0.f, 0.f, 0.f, 0.f};

        #pragma unroll
        for (int ks = 0; ks < KS; ks++) {
            bf16x8 a = *(const bf16x8*)(xrow + ks * 32);
            #pragma unroll
            for (int nf = 0; nf < NFW; nf++) {
                int gnf = wn * NFW + nf;
                const u16* bp = Wf + (((ks * NF + gnf) * 16 + l15) << 5) + (l4 << 3);
                bf16x8 b = *(const bf16x8*)bp;
                acc[nf] = __builtin_amdgcn_mfma_f32_16x16x32_bf16(a, b, acc[nf], 0, 0, 0);
            }
        }

        // scale by basis, transpose via LDS
        #pragma unroll
        for (int nf = 0; nf < NFW; nf++) {
            int col = (wn * NFW + nf) * 16 + l15;
            #pragma unroll
            for (int r = 0; r < 4; r++) {
                int pl = wm * 16 + l4 * 4 + r;
                tbuf[pl * STR + col] = f2bf(acc[nf][r] * bas[pl]);
            }
        }
        __syncthreads();

        // coalesced store: np rows of OUT16 bf16 to mpart (bucket-slot order)
        for (int idx = t; idx < np * CH; idx += 256) {
            int row = idx / CH, ch = idx % CH;
            *(bf16x8*)(mpart + (size_t)(t0 + row) * OUT16 + ch * 8) =
                *(const bf16x8*)&tbuf[row * STR + ch * 8];
        }
        __syncthreads();
    }
}

// ---------------- wave-per-bucket conv for ks=7 (IN=64, OUT=13) ----------------
__global__ __launch_bounds__(256) void conv_mfma_w7(
    const u16* __restrict__ xbf, const int* __restrict__ src,
    const float* __restrict__ W, const int* __restrict__ offs,
    const int* __restrict__ pairE, const float* __restrict__ pairB,
    u16* __restrict__ mpart, int K) {
    constexpr int IN = 64, OUT = 13, OUT16 = 16;
    __shared__ u16 WfAll[4][IN * OUT16];   // 2 KB per wave
    __shared__ u16 tbAll[4][16 * 24];      // padded transpose buf
    int t = threadIdx.x, wid = t >> 6, lane = t & 63;
    int k = blockIdx.x * 4 + wid;
    if (k >= K) return;
    int p0 = offs[k], p1 = offs[k + 1];
    if (p0 >= p1) return;
    u16* Wf = WfAll[wid];
    u16* tb = tbAll[wid];

    const float* Wg = W + (size_t)k * (IN * OUT);
    for (int f = lane; f < IN * OUT16; f += 64) {
        int i = f >> 4, o = f & 15;
        float v = (o < OUT) ? Wg[i * OUT + o] : 0.0f;
        int ks = i >> 5, koct = (i >> 3) & 3, j = i & 7;
        Wf[(((ks)*16 + o) << 5) + (koct << 3) + j] = f2bf(v);
    }
    int l15 = lane & 15, l4 = lane >> 4;
    for (int t0 = p0; t0 < p1; t0 += 16) {
        int np = min(16, p1 - t0);
        int pr = (l15 < np) ? l15 : 0;
        int node = src[pairE[t0 + pr]];
        const u16* xrow = xbf + (size_t)node * IN + l4 * 8;
        f32x4 acc = f32x4{0.f, 0.f, 0.f, 0.f};
        #pragma unroll
        for (int ks = 0; ks < 2; ks++) {
            bf16x8 a = *(const bf16x8*)(xrow + ks * 32);
            bf16x8 b = *(const bf16x8*)&Wf[((ks * 16 + l15) << 5) + (l4 << 3)];
            acc = __builtin_amdgcn_mfma_f32_16x16x32_bf16(a, b, acc, 0, 0, 0);
        }
        #pragma unroll
        for (int r = 0; r < 4; r++) {
            int pl = l4 * 4 + r;
            float bsv = (pl < np) ? pairB[t0 + pl] : 0.0f;
            tb[pl * 24 + l15] = f2bf(acc[r] * bsv);
        }
        if (lane < np * 2) {
            int row = lane >> 1, ch = lane & 1;
            *(bf16x8*)(mpart + (size_t)(t0 + row) * OUT16 + ch * 8) =
                *(const bf16x8*)&tb[row * 24 + ch * 8];
        }
    }
}

// ---------------- gather segment reduce + mean + root + bias ----------------
template <int IN, int OUT, int OUT16>
__global__ __launch_bounds__(256) void reduce_mfma(
    const u16* __restrict__ mpart, const int* __restrict__ perm,
    const int* __restrict__ eoff, const float* __restrict__ xin,
    const float* __restrict__ Wr, const float* __restrict__ bias,
    float* __restrict__ hout, u16* __restrict__ hbf, int N) {
    int n = blockIdx.x;
    int e0 = eoff[n], e1 = eoff[n + 1];
    int R = (e1 - e0) * SCOR;
    size_t rs = (size_t)e0 * SCOR;
    constexpr int CH = OUT16 / 8;
    constexpr int G = 256 / CH;
    int t = threadIdx.x;
    int ch = t % CH, rg = t / CH;
    float a[8] = {0, 0, 0, 0, 0, 0, 0, 0};
    for (int r = rg; r < R; r += G) {
        int slot = perm[rs + r];
        const u16* mp = mpart + (size_t)slot * OUT16 + ch * 8;
        bf16x8 v = *(const bf16x8*)mp;
        #pragma unroll
        for (int j = 0; j < 8; j++) a[j] += bf2f(((const u16*)&v)[j]);
    }
    __shared__ float part[256 * 9];
    #pragma unroll
    for (int j = 0; j < 8; j++) part[t * 9 + j] = a[j];
    __syncthreads();
    // tree reduce over row-groups
    for (int h = G / 2; h >= 1; h >>= 1) {
        if (rg < h) {
            #pragma unroll
            for (int j = 0; j < 8; j++)
                part[t * 9 + j] += part[(t + h * CH) * 9 + j];
        }
        __syncthreads();
    }
    if (t < OUT) {
        int och = t / 8, oj = t % 8;
        float s = part[och * 9 + oj];
        int dg = e1 - e0;
        s /= (dg < 1) ? 1.0f : (float)dg;
        s += bias[t];
        const float* xr = xin + (size_t)n * IN;
        #pragma unroll 8
        for (int i = 0; i < IN; i++) s += xr[i] * Wr[i * OUT + t];
        hout[(size_t)n * OUT + t] = s;
        if (hbf) hbf[(size_t)n * OUT + t] = f2bf(s);
    }
}

// ---------------- ELU + log_softmax (13 classes) ----------------
__global__ __launch_bounds__(256) void head_kernel(const float* __restrict__ h,
                                                   float* __restrict__ out, int N) {
    int n = blockIdx.x * blockDim.x + threadIdx.x;
    if (n >= N) return;
    float v[13];
    float mx = -1e30f;
    #pragma unroll
    for (int c = 0; c < 13; c++) {
        float z = h[n * 13 + c];
        z = z > 0.0f ? z : (expf(z) - 1.0f);
        v[c] = z;
        mx = fmaxf(mx, z);
    }
    float sum = 0.0f;
    #pragma unroll
    for (int c = 0; c < 13; c++) sum += expf(v[c] - mx);
    float lse = mx + logf(sum);
    #pragma unroll
    for (int c = 0; c < 13; c++) out[n * 13 + c] = v[c] - lse;
}

extern "C" void kernel_launch(void* const* d_in, const int* in_sizes, int n_in,
                              void* d_out, int out_size, void* d_ws, size_t ws_size,
                              hipStream_t stream) {
    const float* x   = (const float*)d_in[0];
    const int*   ei  = (const int*)d_in[1];
    const float* ea  = (const float*)d_in[2];
    const float* W1  = (const float*)d_in[3];
    const float* Wr1 = (const float*)d_in[4];
    const float* b1  = (const float*)d_in[5];
    const float* W3  = (const float*)d_in[6];
    const float* Wr3 = (const float*)d_in[7];
    const float* b3  = (const float*)d_in[8];
    const float* W6  = (const float*)d_in[9];
    const float* Wr6 = (const float*)d_in[10];
    const float* b6  = (const float*)d_in[11];
    const float* W7  = (const float*)d_in[12];
    const float* Wr7 = (const float*)d_in[13];
    const float* b7  = (const float*)d_in[14];

    const int N = in_sizes[0] / 32;
    const int E = in_sizes[1] / 2;
    const int* src = ei;
    const int* dst = ei + E;
    (void)n_in; (void)out_size; (void)ws_size;

    const int K3 = 729, K5 = 15625, K7 = 117649;

    char* ws = (char*)d_ws;
    size_t off = 0;
    auto alloc = [&](size_t bytes) {
        void* p = ws + off;
        off += (bytes + 255) & ~(size_t)255;
        return p;
    };
    int*   degi  = (int*)alloc((size_t)N * 4);
    int*   eoff  = (int*)alloc((size_t)(N + 1) * 4);
    int*   erank = (int*)alloc((size_t)E * 4);
    int*   cnt   = (int*)alloc((size_t)K7 * 4);
    int*   offsb = (int*)alloc((size_t)(K7 + 1) * 4);
    int*   pairE = (int*)alloc((size_t)E * SCOR * 4);
    float* pairB = (float*)alloc((size_t)E * SCOR * 4);
    int*   perm  = (int*)alloc((size_t)E * SCOR * 4);
    float* h1    = (float*)alloc((size_t)N * 128 * 4);
    float* h3    = (float*)alloc((size_t)N * 128 * 4);
    float* h6    = (float*)alloc((size_t)N * 64 * 4);
    float* h7    = (float*)alloc((size_t)N * 13 * 4);
    u16*   xbf1  = (u16*)alloc((size_t)N * 32 * 2);
    u16*   hbf1  = (u16*)alloc((size_t)N * 128 * 2);
    u16*   hbf3  = (u16*)alloc((size_t)N * 128 * 2);
    u16*   hbf6  = (u16*)alloc((size_t)N * 64 * 2);
    u16*   mpart = (u16*)alloc((size_t)E * SCOR * 128 * 2);  // 256 MiB

    dim3 blk(256);
    dim3 egrid((E + 255) / 256);

    // x -> bf16
    tobf_kernel<<<(N * 32 / 4 + 255) / 256, blk, 0, stream>>>(x, xbf1, N * 32 / 4);

    // degree / dst-sorted edge ranks
    hipMemsetAsync(degi, 0, (size_t)N * 4, stream);
    deg_kernel<<<egrid, blk, 0, stream>>>(dst, degi, E);
    scan_kernel<<<1, 1024, 0, stream>>>(degi, eoff, N);
    erank_kernel<<<egrid, blk, 0, stream>>>(dst, degi, erank, E);

    // ---- ks=3 buckets (layers 1 & 3) ----
    hipMemsetAsync(cnt, 0, (size_t)K3 * 4, stream);
    count_kernel<3><<<egrid, blk, 0, stream>>>(ea, cnt, E);
    scan_kernel<<<1, 1024, 0, stream>>>(cnt, offsb, K3);
    fill_kernel<3><<<egrid, blk, 0, stream>>>(ea, cnt, erank, pairE, pairB, perm, E);

    // layer 1: 32 -> 128
    conv_mfma<32, 128, 2, 2, 8><<<dim3(K3, 8), blk, 32 * 128 * 2 + 32 * 136 * 2 + 256, stream>>>(
        xbf1, src, W1, offsb, pairE, pairB, mpart);
    reduce_mfma<32, 128, 128><<<N, blk, 0, stream>>>(mpart, perm, eoff, x, Wr1, b1, h1, hbf1, N);

    // layer 3: 128 -> 128
    conv_mfma<128, 128, 2, 2, 8><<<dim3(K3, 8), blk, 128 * 128 * 2 + 32 * 136 * 2 + 256, stream>>>(
        hbf1, src, W3, offsb, pairE, pairB, mpart);
    reduce_mfma<128, 128, 128><<<N, blk, 0, stream>>>(mpart, perm, eoff, h1, Wr3, b3, h3, hbf3, N);

    // ---- ks=5 buckets ----
    hipMemsetAsync(cnt, 0, (size_t)K5 * 4, stream);
    count_kernel<5><<<egrid, blk, 0, stream>>>(ea, cnt, E);
    scan_kernel<<<1, 1024, 0, stream>>>(cnt, offsb, K5);
    fill_kernel<5><<<egrid, blk, 0, stream>>>(ea, cnt, erank, pairE, pairB, perm, E);

    // layer 6: 128 -> 64
    conv_mfma<128, 64, 2, 2, 1><<<dim3(K5, 1), blk, 128 * 64 * 2 + 32 * 72 * 2 + 256, stream>>>(
        hbf3, src, W6, offsb, pairE, pairB, mpart);
    reduce_mfma<128, 64, 64><<<N, blk, 0, stream>>>(mpart, perm, eoff, h3, Wr6, b6, h6, hbf6, N);

    // ---- ks=7 buckets ----
    hipMemsetAsync(cnt, 0, (size_t)K7 * 4, stream);
    count_kernel<7><<<egrid, blk, 0, stream>>>(ea, cnt, E);
    scan_kernel<<<1, 1024, 0, stream>>>(cnt, offsb, K7);
    fill_kernel<7><<<egrid, blk, 0, stream>>>(ea, cnt, erank, pairE, pairB, perm, E);

    // layer 7: 64 -> 13 (wave per bucket)
    conv_mfma_w7<<<(K7 + 3) / 4, blk, 0, stream>>>(hbf6, src, W7, offsb, pairE, pairB, mpart, K7);
    reduce_mfma<64, 13, 16><<<N, blk, 0, stream>>>(mpart, perm, eoff, h6, Wr7, b7, h7, nullptr, N);

    // ELU + log_softmax
    head_kernel<<<(N + 255) / 256, blk, 0, stream>>>(h7, (float*)d_out, N);
}

// Round 4
// 1927.234 us; speedup vs baseline: 4.8825x; 1.4970x over previous
//
#include <hip/hip_runtime.h>
#include <hip/hip_bf16.h>
#include <cstdint>
#include <cstddef>

constexpr int SDIM = 6;
constexpr int SCOR = 64;   // 2^6 corners
typedef unsigned short u16;
typedef __attribute__((ext_vector_type(8))) short bf16x8;
typedef __attribute__((ext_vector_type(4))) float f32x4;

__device__ __forceinline__ float bf2f(u16 h) {
    union { unsigned u; float f; } v; v.u = ((unsigned)h) << 16; return v.f;
}
__device__ __forceinline__ u16 f2bf(float f) {
    union { float f; unsigned u; } v; v.f = f;
    unsigned r = v.u + 0x7fffu + ((v.u >> 16) & 1u);
    return (u16)(r >> 16);
}

// ---------------- fp32 -> bf16 convert ----------------
__global__ __launch_bounds__(256) void tobf_kernel(const float* __restrict__ in,
                                                   u16* __restrict__ out, int n4) {
    int i = blockIdx.x * blockDim.x + threadIdx.x;
    if (i < n4) {
        float4 v = ((const float4*)in)[i];
        ushort4 o;
        o.x = f2bf(v.x); o.y = f2bf(v.y); o.z = f2bf(v.z); o.w = f2bf(v.w);
        ((ushort4*)out)[i] = o;
    }
}

// ---------------- degree ----------------
__global__ __launch_bounds__(256) void deg_kernel(const int* __restrict__ dst,
                                                  int* __restrict__ degi, int E) {
    int e = blockIdx.x * blockDim.x + threadIdx.x;
    if (e < E) atomicAdd(&degi[dst[e]], 1);
}

__global__ __launch_bounds__(256) void erank_kernel(const int* __restrict__ dst,
                                                    int* __restrict__ cursor,
                                                    int* __restrict__ erank, int E) {
    int e = blockIdx.x * blockDim.x + threadIdx.x;
    if (e < E) erank[e] = atomicAdd(&cursor[dst[e]], 1);
}

// ---------------- bucketing (pair-parallel: one thread per (edge,corner)) ----------------
template <int KS>
__global__ __launch_bounds__(256) void count_kernel(const float* __restrict__ ea,
                                                    int* __restrict__ counts, int P) {
    int gid = blockIdx.x * blockDim.x + threadIdx.x;
    if (gid >= P) return;
    int e = gid >> 6, s = gid & 63;
    int idx = 0, str = 1;
    #pragma unroll
    for (int d = 0; d < SDIM; d++) {
        float v = ea[e * SDIM + d] * (KS - 1);
        int lo = (int)floorf(v);
        int pos = lo + ((s >> d) & 1);
        pos = min(max(pos, 0), KS - 1);
        idx += pos * str;
        str *= KS;
    }
    atomicAdd(&counts[idx], 1);
}

// fill: slot -> packed {edge, basis}; perm: dst-sorted pair index -> slot
template <int KS>
__global__ __launch_bounds__(256) void fill_kernel(const float* __restrict__ ea,
                                                   int* __restrict__ cursor,
                                                   const int* __restrict__ erank,
                                                   int2* __restrict__ pairEB,
                                                   int* __restrict__ perm, int P) {
    int gid = blockIdx.x * blockDim.x + threadIdx.x;
    if (gid >= P) return;
    int e = gid >> 6, s = gid & 63;
    int idx = 0, str = 1;
    float basis = 1.0f;
    #pragma unroll
    for (int d = 0; d < SDIM; d++) {
        float v = ea[e * SDIM + d] * (KS - 1);
        float fl = floorf(v);
        float fr = v - fl;
        int bit = (s >> d) & 1;
        int pos = (int)fl + bit;
        pos = min(max(pos, 0), KS - 1);
        idx += pos * str;
        str *= KS;
        basis *= bit ? fr : (1.0f - fr);
    }
    int slot = atomicAdd(&cursor[idx], 1);
    int2 eb;
    eb.x = e;
    eb.y = __float_as_int(basis);
    pairEB[slot] = eb;
    perm[erank[e] * SCOR + s] = slot;
}

// single-block exclusive scan; counts becomes the fill cursor (= offs)
__global__ __launch_bounds__(1024) void scan_kernel(int* __restrict__ counts,
                                                    int* __restrict__ offs, int K) {
    __shared__ int sums[1024];
    int t = threadIdx.x;
    int chunk = (K + 1023) / 1024;
    int a0 = t * chunk;
    int a1 = min(a0 + chunk, K);
    int s = 0;
    for (int j = a0; j < a1; j++) s += counts[j];
    sums[t] = s;
    __syncthreads();
    for (int off = 1; off < 1024; off <<= 1) {
        int v = (t >= off) ? sums[t - off] : 0;
        __syncthreads();
        sums[t] += v;
        __syncthreads();
    }
    int run = (t == 0) ? 0 : sums[t - 1];
    for (int j = a0; j < a1; j++) {
        int c = counts[j];
        offs[j] = run;
        counts[j] = run;  // cursor init
        run += c;
    }
    if (t == 1023) offs[K] = run;
}

// ---------------- MFMA bucketed conv ----------------
template <int IN, int OUT, int WM, int WN, int GY>
__global__ __launch_bounds__(256) void conv_mfma(
    const u16* __restrict__ xbf, const int* __restrict__ src,
    const float* __restrict__ W, const int* __restrict__ offs,
    const int2* __restrict__ pairEB, u16* __restrict__ mpart) {
    constexpr int OUT16 = (OUT + 15) & ~15;
    constexpr int NF = OUT16 / 16;   // total col-frags
    constexpr int NFW = NF / WN;     // col-frags per wave
    constexpr int MT = WM * 16;      // pairs per tile
    constexpr int KS = IN / 32;      // k-steps
    constexpr int STR = OUT16 + 8;   // tbuf stride (u16)
    constexpr int CH = OUT16 / 8;    // 16B chunks per row

    extern __shared__ char lds[];
    u16* Wf = (u16*)lds;                                     // IN*OUT16
    u16* tbuf = (u16*)(lds + IN * OUT16 * 2);                // MT*STR
    int* sE = (int*)(lds + IN * OUT16 * 2 + MT * STR * 2);   // MT
    float* bas = (float*)(sE + MT);                          // MT

    int k = blockIdx.x;
    int p0 = offs[k], p1 = offs[k + 1];
    if (p0 + MT * (int)blockIdx.y >= p1) return;

    int t = threadIdx.x;
    // stage W[k]: fp32 row-major [IN][OUT] -> bf16 fragment order
    const float* Wg = W + (size_t)k * IN * OUT;
    for (int f = t; f < IN * OUT16; f += 256) {
        int i = f / OUT16, o = f % OUT16;
        float v = (OUT == OUT16 || o < OUT) ? Wg[i * OUT + o] : 0.0f;
        int ks = i >> 5, koct = (i >> 3) & 3, j = i & 7, nf = o >> 4, c = o & 15;
        Wf[(((ks * NF + nf) * 16 + c) << 5) + (koct << 3) + j] = f2bf(v);
    }
    __syncthreads();

    int wid = t >> 6, lane = t & 63;
    int wm = wid % WM, wn = wid / WM;
    int l15 = lane & 15, l4 = lane >> 4;

    for (int t0 = p0 + MT * blockIdx.y; t0 < p1; t0 += MT * GY) {
        int np = min(MT, p1 - t0);
        if (t < MT) {
            int pp = t0 + t;
            if (pp < p1) {
                int2 eb = pairEB[pp];
                sE[t] = src[eb.x];
                bas[t] = __int_as_float(eb.y);
            } else {
                sE[t] = 0;
                bas[t] = 0.0f;
            }
        }
        __syncthreads();

        int prow = wm * 16 + l15;
        int node = sE[prow < np ? prow : 0];
        const u16* xrow = xbf + (size_t)node * IN + l4 * 8;

        f32x4 acc[NFW];
        #pragma unroll
        for (int nf = 0; nf < NFW; nf++)
            acc[nf] = f32x4{0.f, 0.f, 0.f, 0.f};

        #pragma unroll
        for (int ks = 0; ks < KS; ks++) {
            bf16x8 a = *(const bf16x8*)(xrow + ks * 32);
            #pragma unroll
            for (int nf = 0; nf < NFW; nf++) {
                int gnf = wn * NFW + nf;
                const u16* bp = Wf + (((ks * NF + gnf) * 16 + l15) << 5) + (l4 << 3);
                bf16x8 b = *(const bf16x8*)bp;
                acc[nf] = __builtin_amdgcn_mfma_f32_16x16x32_bf16(a, b, acc[nf], 0, 0, 0);
            }
        }

        // scale by basis, transpose via LDS
        #pragma unroll
        for (int nf = 0; nf < NFW; nf++) {
            int col = (wn * NFW + nf) * 16 + l15;
            #pragma unroll
            for (int r = 0; r < 4; r++) {
                int pl = wm * 16 + l4 * 4 + r;
                tbuf[pl * STR + col] = f2bf(acc[nf][r] * bas[pl]);
            }
        }
        __syncthreads();

        // coalesced store: np rows of OUT16 bf16 to mpart (bucket-slot order)
        for (int idx = t; idx < np * CH; idx += 256) {
            int row = idx / CH, ch = idx % CH;
            *(bf16x8*)(mpart + (size_t)(t0 + row) * OUT16 + ch * 8) =
                *(const bf16x8*)&tbuf[row * STR + ch * 8];
        }
        __syncthreads();
    }
}

// ---------------- wave-per-bucket conv for ks=7 (IN=64, OUT=13) ----------------
__global__ __launch_bounds__(256) void conv_mfma_w7(
    const u16* __restrict__ xbf, const int* __restrict__ src,
    const float* __restrict__ W, const int* __restrict__ offs,
    const int2* __restrict__ pairEB, u16* __restrict__ mpart, int K) {
    constexpr int IN = 64, OUT = 13, OUT16 = 16;
    __shared__ u16 WfAll[4][IN * OUT16];   // 2 KB per wave
    __shared__ u16 tbAll[4][16 * 24];      // padded transpose buf
    int t = threadIdx.x, wid = t >> 6, lane = t & 63;
    int k = blockIdx.x * 4 + wid;
    if (k >= K) return;
    int p0 = offs[k], p1 = offs[k + 1];
    if (p0 >= p1) return;
    u16* Wf = WfAll[wid];
    u16* tb = tbAll[wid];

    const float* Wg = W + (size_t)k * (IN * OUT);
    for (int f = lane; f < IN * OUT16; f += 64) {
        int i = f >> 4, o = f & 15;
        float v = (o < OUT) ? Wg[i * OUT + o] : 0.0f;
        int ks = i >> 5, koct = (i >> 3) & 3, j = i & 7;
        Wf[(((ks)*16 + o) << 5) + (koct << 3) + j] = f2bf(v);
    }
    int l15 = lane & 15, l4 = lane >> 4;
    for (int t0 = p0; t0 < p1; t0 += 16) {
        int np = min(16, p1 - t0);
        int pr = (l15 < np) ? l15 : 0;
        int node = src[pairEB[t0 + pr].x];
        const u16* xrow = xbf + (size_t)node * IN + l4 * 8;
        f32x4 acc = f32x4{0.f, 0.f, 0.f, 0.f};
        #pragma unroll
        for (int ks = 0; ks < 2; ks++) {
            bf16x8 a = *(const bf16x8*)(xrow + ks * 32);
            bf16x8 b = *(const bf16x8*)&Wf[((ks * 16 + l15) << 5) + (l4 << 3)];
            acc = __builtin_amdgcn_mfma_f32_16x16x32_bf16(a, b, acc, 0, 0, 0);
        }
        #pragma unroll
        for (int r = 0; r < 4; r++) {
            int pl = l4 * 4 + r;
            float bsv = (pl < np) ? __int_as_float(pairEB[t0 + pl].y) : 0.0f;
            tb[pl * 24 + l15] = f2bf(acc[r] * bsv);
        }
        if (lane < np * 2) {
            int row = lane >> 1, ch = lane & 1;
            *(bf16x8*)(mpart + (size_t)(t0 + row) * OUT16 + ch * 8) =
                *(const bf16x8*)&tb[row * 24 + ch * 8];
        }
    }
}

// ---------------- gather segment reduce + mean + root + bias ----------------
template <int IN, int OUT, int OUT16>
__global__ __launch_bounds__(256) void reduce_mfma(
    const u16* __restrict__ mpart, const int* __restrict__ perm,
    const int* __restrict__ eoff, const float* __restrict__ xin,
    const float* __restrict__ Wr, const float* __restrict__ bias,
    float* __restrict__ hout, u16* __restrict__ hbf, int N) {
    int n = blockIdx.x;
    int e0 = eoff[n], e1 = eoff[n + 1];
    int R = (e1 - e0) * SCOR;
    size_t rs = (size_t)e0 * SCOR;
    constexpr int CH = OUT16 / 8;
    constexpr int G = 256 / CH;
    int t = threadIdx.x;
    int ch = t % CH, rg = t / CH;
    float a[8] = {0, 0, 0, 0, 0, 0, 0, 0};
    for (int r = rg; r < R; r += G) {
        int slot = perm[rs + r];
        const u16* mp = mpart + (size_t)slot * OUT16 + ch * 8;
        bf16x8 v = *(const bf16x8*)mp;
        #pragma unroll
        for (int j = 0; j < 8; j++) a[j] += bf2f(((const u16*)&v)[j]);
    }
    __shared__ float part[256 * 9];
    #pragma unroll
    for (int j = 0; j < 8; j++) part[t * 9 + j] = a[j];
    __syncthreads();
    for (int h = G / 2; h >= 1; h >>= 1) {
        if (rg < h) {
            #pragma unroll
            for (int j = 0; j < 8; j++)
                part[t * 9 + j] += part[(t + h * CH) * 9 + j];
        }
        __syncthreads();
    }
    if (t < OUT) {
        int och = t / 8, oj = t % 8;
        float s = part[och * 9 + oj];
        int dg = e1 - e0;
        s /= (dg < 1) ? 1.0f : (float)dg;
        s += bias[t];
        const float* xr = xin + (size_t)n * IN;
        #pragma unroll 8
        for (int i = 0; i < IN; i++) s += xr[i] * Wr[i * OUT + t];
        hout[(size_t)n * OUT + t] = s;
        if (hbf) hbf[(size_t)n * OUT + t] = f2bf(s);
    }
}

// ---------------- ELU + log_softmax (13 classes) ----------------
__global__ __launch_bounds__(256) void head_kernel(const float* __restrict__ h,
                                                   float* __restrict__ out, int N) {
    int n = blockIdx.x * blockDim.x + threadIdx.x;
    if (n >= N) return;
    float v[13];
    float mx = -1e30f;
    #pragma unroll
    for (int c = 0; c < 13; c++) {
        float z = h[n * 13 + c];
        z = z > 0.0f ? z : (expf(z) - 1.0f);
        v[c] = z;
        mx = fmaxf(mx, z);
    }
    float sum = 0.0f;
    #pragma unroll
    for (int c = 0; c < 13; c++) sum += expf(v[c] - mx);
    float lse = mx + logf(sum);
    #pragma unroll
    for (int c = 0; c < 13; c++) out[n * 13 + c] = v[c] - lse;
}

extern "C" void kernel_launch(void* const* d_in, const int* in_sizes, int n_in,
                              void* d_out, int out_size, void* d_ws, size_t ws_size,
                              hipStream_t stream) {
    const float* x   = (const float*)d_in[0];
    const int*   ei  = (const int*)d_in[1];
    const float* ea  = (const float*)d_in[2];
    const float* W1  = (const float*)d_in[3];
    const float* Wr1 = (const float*)d_in[4];
    const float* b1  = (const float*)d_in[5];
    const float* W3  = (const float*)d_in[6];
    const float* Wr3 = (const float*)d_in[7];
    const float* b3  = (const float*)d_in[8];
    const float* W6  = (const float*)d_in[9];
    const float* Wr6 = (const float*)d_in[10];
    const float* b6  = (const float*)d_in[11];
    const float* W7  = (const float*)d_in[12];
    const float* Wr7 = (const float*)d_in[13];
    const float* b7  = (const float*)d_in[14];

    const int N = in_sizes[0] / 32;
    const int E = in_sizes[1] / 2;
    const int* src = ei;
    const int* dst = ei + E;
    (void)n_in; (void)out_size; (void)ws_size;

    const int K3 = 729, K5 = 15625, K7 = 117649;
    const int P = E * SCOR;

    char* ws = (char*)d_ws;
    size_t off = 0;
    auto alloc = [&](size_t bytes) {
        void* p = ws + off;
        off += (bytes + 255) & ~(size_t)255;
        return p;
    };
    int*   degi  = (int*)alloc((size_t)N * 4);
    int*   eoff  = (int*)alloc((size_t)(N + 1) * 4);
    int*   erank = (int*)alloc((size_t)E * 4);
    int*   cnt   = (int*)alloc((size_t)K7 * 4);
    int*   offsb = (int*)alloc((size_t)(K7 + 1) * 4);
    int2*  pairEB = (int2*)alloc((size_t)P * 8);
    int*   perm  = (int*)alloc((size_t)P * 4);
    float* h1    = (float*)alloc((size_t)N * 128 * 4);
    float* h3    = (float*)alloc((size_t)N * 128 * 4);
    float* h6    = (float*)alloc((size_t)N * 64 * 4);
    float* h7    = (float*)alloc((size_t)N * 13 * 4);
    u16*   xbf1  = (u16*)alloc((size_t)N * 32 * 2);
    u16*   hbf1  = (u16*)alloc((size_t)N * 128 * 2);
    u16*   hbf3  = (u16*)alloc((size_t)N * 128 * 2);
    u16*   hbf6  = (u16*)alloc((size_t)N * 64 * 2);
    u16*   mpart = (u16*)alloc((size_t)P * 128 * 2);  // 256 MiB

    dim3 blk(256);
    dim3 egrid((E + 255) / 256);
    dim3 pgrid((P + 255) / 256);

    // x -> bf16
    tobf_kernel<<<(N * 32 / 4 + 255) / 256, blk, 0, stream>>>(x, xbf1, N * 32 / 4);

    // degree / dst-sorted edge ranks
    hipMemsetAsync(degi, 0, (size_t)N * 4, stream);
    deg_kernel<<<egrid, blk, 0, stream>>>(dst, degi, E);
    scan_kernel<<<1, 1024, 0, stream>>>(degi, eoff, N);
    erank_kernel<<<egrid, blk, 0, stream>>>(dst, degi, erank, E);

    // ---- ks=3 buckets (layers 1 & 3) ----
    hipMemsetAsync(cnt, 0, (size_t)K3 * 4, stream);
    count_kernel<3><<<pgrid, blk, 0, stream>>>(ea, cnt, P);
    scan_kernel<<<1, 1024, 0, stream>>>(cnt, offsb, K3);
    fill_kernel<3><<<pgrid, blk, 0, stream>>>(ea, cnt, erank, pairEB, perm, P);

    // layer 1: 32 -> 128
    conv_mfma<32, 128, 2, 2, 8><<<dim3(K3, 8), blk, 32 * 128 * 2 + 32 * 136 * 2 + 256, stream>>>(
        xbf1, src, W1, offsb, pairEB, mpart);
    reduce_mfma<32, 128, 128><<<N, blk, 0, stream>>>(mpart, perm, eoff, x, Wr1, b1, h1, hbf1, N);

    // layer 3: 128 -> 128
    conv_mfma<128, 128, 2, 2, 8><<<dim3(K3, 8), blk, 128 * 128 * 2 + 32 * 136 * 2 + 256, stream>>>(
        hbf1, src, W3, offsb, pairEB, mpart);
    reduce_mfma<128, 128, 128><<<N, blk, 0, stream>>>(mpart, perm, eoff, h1, Wr3, b3, h3, hbf3, N);

    // ---- ks=5 buckets ----
    hipMemsetAsync(cnt, 0, (size_t)K5 * 4, stream);
    count_kernel<5><<<pgrid, blk, 0, stream>>>(ea, cnt, P);
    scan_kernel<<<1, 1024, 0, stream>>>(cnt, offsb, K5);
    fill_kernel<5><<<pgrid, blk, 0, stream>>>(ea, cnt, erank, pairEB, perm, P);

    // layer 6: 128 -> 64
    conv_mfma<128, 64, 2, 2, 1><<<dim3(K5, 1), blk, 128 * 64 * 2 + 32 * 72 * 2 + 256, stream>>>(
        hbf3, src, W6, offsb, pairEB, mpart);
    reduce_mfma<128, 64, 64><<<N, blk, 0, stream>>>(mpart, perm, eoff, h3, Wr6, b6, h6, hbf6, N);

    // ---- ks=7 buckets ----
    hipMemsetAsync(cnt, 0, (size_t)K7 * 4, stream);
    count_kernel<7><<<pgrid, blk, 0, stream>>>(ea, cnt, P);
    scan_kernel<<<1, 1024, 0, stream>>>(cnt, offsb, K7);
    fill_kernel<7><<<pgrid, blk, 0, stream>>>(ea, cnt, erank, pairEB, perm, P);

    // layer 7: 64 -> 13 (wave per bucket)
    conv_mfma_w7<<<(K7 + 3) / 4, blk, 0, stream>>>(hbf6, src, W7, offsb, pairEB, mpart, K7);
    reduce_mfma<64, 13, 16><<<N, blk, 0, stream>>>(mpart, perm, eoff, h6, Wr7, b7, h7, nullptr, N);

    // ELU + log_softmax
    head_kernel<<<(N + 255) / 256, blk, 0, stream>>>(h7, (float*)d_out, N);
}

// Round 5
// 1741.652 us; speedup vs baseline: 5.4027x; 1.1066x over previous
//
#include <hip/hip_runtime.h>
#include <hip/hip_bf16.h>
#include <cstdint>
#include <cstddef>

constexpr int SDIM = 6;
constexpr int SCOR = 64;   // 2^6 corners
typedef unsigned short u16;
typedef __attribute__((ext_vector_type(8))) short bf16x8;
typedef __attribute__((ext_vector_type(4))) float f32x4;

__device__ __forceinline__ float bf2f(u16 h) {
    union { unsigned u; float f; } v; v.u = ((unsigned)h) << 16; return v.f;
}
__device__ __forceinline__ u16 f2bf(float f) {
    union { float f; unsigned u; } v; v.f = f;
    unsigned r = v.u + 0x7fffu + ((v.u >> 16) & 1u);
    return (u16)(r >> 16);
}

// ---------------- zero helper (avoid hipMemsetAsync ambiguity) ----------------
__global__ __launch_bounds__(256) void zero_kernel(int* __restrict__ p, int n) {
    int i = blockIdx.x * blockDim.x + threadIdx.x;
    if (i < n) p[i] = 0;
}

// ---------------- fp32 -> bf16 convert ----------------
__global__ __launch_bounds__(256) void tobf_kernel(const float* __restrict__ in,
                                                   u16* __restrict__ out, int n4) {
    int i = blockIdx.x * blockDim.x + threadIdx.x;
    if (i < n4) {
        float4 v = ((const float4*)in)[i];
        ushort4 o;
        o.x = f2bf(v.x); o.y = f2bf(v.y); o.z = f2bf(v.z); o.w = f2bf(v.w);
        ((ushort4*)out)[i] = o;
    }
}

// ---------------- degree ----------------
__global__ __launch_bounds__(256) void deg_kernel(const int* __restrict__ dst,
                                                  int* __restrict__ degi, int E) {
    int e = blockIdx.x * blockDim.x + threadIdx.x;
    if (e < E) atomicAdd(&degi[dst[e]], 1);
}

__global__ __launch_bounds__(256) void erank_kernel(const int* __restrict__ dst,
                                                    int* __restrict__ cursor,
                                                    int* __restrict__ erank, int E) {
    int e = blockIdx.x * blockDim.x + threadIdx.x;
    if (e < E) erank[e] = atomicAdd(&cursor[dst[e]], 1);
}

// ---------------- bucketing (pair-parallel) ----------------
template <int KS>
__global__ __launch_bounds__(256) void count_kernel(const float* __restrict__ ea,
                                                    int* __restrict__ counts, int P) {
    int gid = blockIdx.x * blockDim.x + threadIdx.x;
    if (gid >= P) return;
    int e = gid >> 6, s = gid & 63;
    int idx = 0, str = 1;
    #pragma unroll
    for (int d = 0; d < SDIM; d++) {
        float v = ea[e * SDIM + d] * (KS - 1);
        int lo = (int)floorf(v);
        int pos = lo + ((s >> d) & 1);
        pos = min(max(pos, 0), KS - 1);
        idx += pos * str;
        str *= KS;
    }
    atomicAdd(&counts[idx], 1);
}

template <int KS>
__global__ __launch_bounds__(256) void fill_kernel(const float* __restrict__ ea,
                                                   int* __restrict__ cursor,
                                                   const int* __restrict__ erank,
                                                   int2* __restrict__ pairEB,
                                                   int* __restrict__ perm, int P) {
    int gid = blockIdx.x * blockDim.x + threadIdx.x;
    if (gid >= P) return;
    int e = gid >> 6, s = gid & 63;
    int idx = 0, str = 1;
    float basis = 1.0f;
    #pragma unroll
    for (int d = 0; d < SDIM; d++) {
        float v = ea[e * SDIM + d] * (KS - 1);
        float fl = floorf(v);
        float fr = v - fl;
        int bit = (s >> d) & 1;
        int pos = (int)fl + bit;
        pos = min(max(pos, 0), KS - 1);
        idx += pos * str;
        str *= KS;
        basis *= bit ? fr : (1.0f - fr);
    }
    int slot = atomicAdd(&cursor[idx], 1);
    int2 eb;
    eb.x = e;
    eb.y = __float_as_int(basis);
    pairEB[slot] = eb;
    perm[erank[e] * SCOR + s] = slot;
}

// single-block exclusive scan; counts becomes the fill cursor (= offs)
__global__ __launch_bounds__(1024) void scan_kernel(int* __restrict__ counts,
                                                    int* __restrict__ offs, int K) {
    __shared__ int sums[1024];
    int t = threadIdx.x;
    int chunk = (K + 1023) / 1024;
    int a0 = t * chunk;
    int a1 = min(a0 + chunk, K);
    int s = 0;
    for (int j = a0; j < a1; j++) s += counts[j];
    sums[t] = s;
    __syncthreads();
    for (int off = 1; off < 1024; off <<= 1) {
        int v = (t >= off) ? sums[t - off] : 0;
        __syncthreads();
        sums[t] += v;
        __syncthreads();
    }
    int run = (t == 0) ? 0 : sums[t - 1];
    for (int j = a0; j < a1; j++) {
        int c = counts[j];
        offs[j] = run;
        counts[j] = run;  // cursor init
        run += c;
    }
    if (t == 1023) offs[K] = run;
}

// ---------------- MFMA bucketed conv, B-fragments in registers ----------------
// Per block: gather this wave's B-fragments once from fp32 W (coalesced 64B
// lines across 16-lane groups), convert to bf16 in-register. Main loop:
// A-frag 16B global load per lane + MFMA only. LDS only for the output
// transpose + sE/bas staging.
template <int IN, int OUT, int WM, int WN, int GY>
__global__ __launch_bounds__(256) void conv_mfma_r(
    const u16* __restrict__ xbf, const int* __restrict__ src,
    const float* __restrict__ W, const int* __restrict__ offs,
    const int2* __restrict__ pairEB, u16* __restrict__ mpart) {
    constexpr int OUT16 = (OUT + 15) & ~15;
    constexpr int NF = OUT16 / 16;   // total col-frags
    constexpr int NFW = NF / WN;     // col-frags per wave
    constexpr int MT = WM * 16;      // pairs per tile
    constexpr int KS = IN / 32;      // k-steps
    constexpr int STR = OUT16 + 8;   // tbuf stride (u16), 16B-aligned rows
    constexpr int CH = OUT16 / 8;    // 16B chunks per row

    __shared__ u16 tbuf[MT * STR];
    __shared__ int sE[MT];
    __shared__ float bas[MT];

    int k = blockIdx.x;
    int p0 = offs[k], p1 = offs[k + 1];
    if (p0 + MT * (int)blockIdx.y >= p1) return;

    int t = threadIdx.x;
    int wid = t >> 6, lane = t & 63;
    int wm = wid % WM, wn = wid / WM;
    int l15 = lane & 15, l4 = lane >> 4;

    // gather B fragments into registers (once per block)
    const float* Wg = W + (size_t)k * IN * OUT;
    bf16x8 breg[KS][NFW];
    #pragma unroll
    for (int ks = 0; ks < KS; ks++) {
        #pragma unroll
        for (int nf = 0; nf < NFW; nf++) {
            int col = (wn * NFW + nf) * 16 + l15;
            bool ok = (OUT == OUT16) || (col < OUT);
            int rbase = ks * 32 + l4 * 8;
            bf16x8 b;
            #pragma unroll
            for (int j = 0; j < 8; j++) {
                float v = ok ? Wg[(rbase + j) * OUT + col] : 0.0f;
                ((u16*)&b)[j] = f2bf(v);
            }
            breg[ks][nf] = b;
        }
    }

    for (int t0 = p0 + MT * blockIdx.y; t0 < p1; t0 += MT * GY) {
        int np = min(MT, p1 - t0);
        if (t < MT) {
            int pp = t0 + t;
            if (pp < p1) {
                int2 eb = pairEB[pp];
                sE[t] = src[eb.x];
                bas[t] = __int_as_float(eb.y);
            } else {
                sE[t] = 0;
                bas[t] = 0.0f;
            }
        }
        __syncthreads();

        int prow = wm * 16 + l15;
        int node = sE[prow < np ? prow : 0];
        const u16* xrow = xbf + (size_t)node * IN + l4 * 8;

        f32x4 acc[NFW];
        #pragma unroll
        for (int nf = 0; nf < NFW; nf++)
            acc[nf] = f32x4{0.f, 0.f, 0.f, 0.f};

        #pragma unroll
        for (int ks = 0; ks < KS; ks++) {
            bf16x8 a = *(const bf16x8*)(xrow + ks * 32);
            #pragma unroll
            for (int nf = 0; nf < NFW; nf++)
                acc[nf] = __builtin_amdgcn_mfma_f32_16x16x32_bf16(a, breg[ks][nf], acc[nf], 0, 0, 0);
        }

        // scale by basis, transpose via LDS
        #pragma unroll
        for (int nf = 0; nf < NFW; nf++) {
            int col = (wn * NFW + nf) * 16 + l15;
            #pragma unroll
            for (int r = 0; r < 4; r++) {
                int pl = wm * 16 + l4 * 4 + r;
                tbuf[pl * STR + col] = f2bf(acc[nf][r] * bas[pl]);
            }
        }
        __syncthreads();

        // coalesced store: np rows of OUT16 bf16 to mpart (bucket-slot order)
        for (int idx = t; idx < np * CH; idx += 256) {
            int row = idx / CH, ch = idx % CH;
            *(bf16x8*)(mpart + (size_t)(t0 + row) * OUT16 + ch * 8) =
                *(const bf16x8*)&tbuf[row * STR + ch * 8];
        }
        __syncthreads();
    }
}

// ---------------- wave-per-bucket conv for ks=7 (IN=64, OUT=13), reg B ----------------
__global__ __launch_bounds__(256) void conv_mfma_w7(
    const u16* __restrict__ xbf, const int* __restrict__ src,
    const float* __restrict__ W, const int* __restrict__ offs,
    const int2* __restrict__ pairEB, u16* __restrict__ mpart, int K) {
    constexpr int IN = 64, OUT = 13, OUT16 = 16;
    __shared__ u16 tbAll[4][16 * 24];
    int t = threadIdx.x, wid = t >> 6, lane = t & 63;
    int k = blockIdx.x * 4 + wid;
    if (k >= K) return;
    int p0 = offs[k], p1 = offs[k + 1];
    if (p0 >= p1) return;
    u16* tb = tbAll[wid];

    int l15 = lane & 15, l4 = lane >> 4;
    const float* Wg = W + (size_t)k * (IN * OUT);
    bf16x8 breg[2];
    #pragma unroll
    for (int ks = 0; ks < 2; ks++) {
        bf16x8 b;
        int rbase = ks * 32 + l4 * 8;
        #pragma unroll
        for (int j = 0; j < 8; j++) {
            float v = (l15 < OUT) ? Wg[(rbase + j) * OUT + l15] : 0.0f;
            ((u16*)&b)[j] = f2bf(v);
        }
        breg[ks] = b;
    }

    for (int t0 = p0; t0 < p1; t0 += 16) {
        int np = min(16, p1 - t0);
        int pr = (l15 < np) ? l15 : 0;
        int node = src[pairEB[t0 + pr].x];
        const u16* xrow = xbf + (size_t)node * IN + l4 * 8;
        f32x4 acc = f32x4{0.f, 0.f, 0.f, 0.f};
        #pragma unroll
        for (int ks = 0; ks < 2; ks++) {
            bf16x8 a = *(const bf16x8*)(xrow + ks * 32);
            acc = __builtin_amdgcn_mfma_f32_16x16x32_bf16(a, breg[ks], acc, 0, 0, 0);
        }
        #pragma unroll
        for (int r = 0; r < 4; r++) {
            int pl = l4 * 4 + r;
            float bsv = (pl < np) ? __int_as_float(pairEB[t0 + pl].y) : 0.0f;
            tb[pl * 24 + l15] = f2bf(acc[r] * bsv);
        }
        if (lane < np * 2) {
            int row = lane >> 1, ch = lane & 1;
            *(bf16x8*)(mpart + (size_t)(t0 + row) * OUT16 + ch * 8) =
                *(const bf16x8*)&tb[row * 24 + ch * 8];
        }
    }
}

// ---------------- gather segment reduce + mean + root + bias ----------------
template <int IN, int OUT, int OUT16>
__global__ __launch_bounds__(256) void reduce_mfma(
    const u16* __restrict__ mpart, const int* __restrict__ perm,
    const int* __restrict__ eoff, const float* __restrict__ xin,
    const float* __restrict__ Wr, const float* __restrict__ bias,
    float* __restrict__ hout, u16* __restrict__ hbf, int N) {
    int n = blockIdx.x;
    int e0 = eoff[n], e1 = eoff[n + 1];
    int R = (e1 - e0) * SCOR;
    size_t rs = (size_t)e0 * SCOR;
    constexpr int CH = OUT16 / 8;
    constexpr int G = 256 / CH;
    int t = threadIdx.x;
    int ch = t % CH, rg = t / CH;
    float a[8] = {0, 0, 0, 0, 0, 0, 0, 0};
    for (int r = rg; r < R; r += G) {
        int slot = perm[rs + r];
        const u16* mp = mpart + (size_t)slot * OUT16 + ch * 8;
        bf16x8 v = *(const bf16x8*)mp;
        #pragma unroll
        for (int j = 0; j < 8; j++) a[j] += bf2f(((const u16*)&v)[j]);
    }
    __shared__ float part[256 * 9];
    #pragma unroll
    for (int j = 0; j < 8; j++) part[t * 9 + j] = a[j];
    __syncthreads();
    for (int h = G / 2; h >= 1; h >>= 1) {
        if (rg < h) {
            #pragma unroll
            for (int j = 0; j < 8; j++)
                part[t * 9 + j] += part[(t + h * CH) * 9 + j];
        }
        __syncthreads();
    }
    if (t < OUT) {
        int och = t / 8, oj = t % 8;
        float s = part[och * 9 + oj];
        int dg = e1 - e0;
        s /= (dg < 1) ? 1.0f : (float)dg;
        s += bias[t];
        const float* xr = xin + (size_t)n * IN;
        #pragma unroll 8
        for (int i = 0; i < IN; i++) s += xr[i] * Wr[i * OUT + t];
        hout[(size_t)n * OUT + t] = s;
        if (hbf) hbf[(size_t)n * OUT + t] = f2bf(s);
    }
}

// ---------------- ELU + log_softmax (13 classes) ----------------
__global__ __launch_bounds__(256) void head_kernel(const float* __restrict__ h,
                                                   float* __restrict__ out, int N) {
    int n = blockIdx.x * blockDim.x + threadIdx.x;
    if (n >= N) return;
    float v[13];
    float mx = -1e30f;
    #pragma unroll
    for (int c = 0; c < 13; c++) {
        float z = h[n * 13 + c];
        z = z > 0.0f ? z : (expf(z) - 1.0f);
        v[c] = z;
        mx = fmaxf(mx, z);
    }
    float sum = 0.0f;
    #pragma unroll
    for (int c = 0; c < 13; c++) sum += expf(v[c] - mx);
    float lse = mx + logf(sum);
    #pragma unroll
    for (int c = 0; c < 13; c++) out[n * 13 + c] = v[c] - lse;
}

extern "C" void kernel_launch(void* const* d_in, const int* in_sizes, int n_in,
                              void* d_out, int out_size, void* d_ws, size_t ws_size,
                              hipStream_t stream) {
    const float* x   = (const float*)d_in[0];
    const int*   ei  = (const int*)d_in[1];
    const float* ea  = (const float*)d_in[2];
    const float* W1  = (const float*)d_in[3];
    const float* Wr1 = (const float*)d_in[4];
    const float* b1  = (const float*)d_in[5];
    const float* W3  = (const float*)d_in[6];
    const float* Wr3 = (const float*)d_in[7];
    const float* b3  = (const float*)d_in[8];
    const float* W6  = (const float*)d_in[9];
    const float* Wr6 = (const float*)d_in[10];
    const float* b6  = (const float*)d_in[11];
    const float* W7  = (const float*)d_in[12];
    const float* Wr7 = (const float*)d_in[13];
    const float* b7  = (const float*)d_in[14];

    const int N = in_sizes[0] / 32;
    const int E = in_sizes[1] / 2;
    const int* src = ei;
    const int* dst = ei + E;
    (void)n_in; (void)out_size; (void)ws_size;

    const int K3 = 729, K5 = 15625, K7 = 117649;
    const int P = E * SCOR;

    char* ws = (char*)d_ws;
    size_t off = 0;
    auto alloc = [&](size_t bytes) {
        void* p = ws + off;
        off += (bytes + 255) & ~(size_t)255;
        return p;
    };
    int*   degi  = (int*)alloc((size_t)N * 4);
    int*   eoff  = (int*)alloc((size_t)(N + 1) * 4);
    int*   erank = (int*)alloc((size_t)E * 4);
    int*   cnt   = (int*)alloc((size_t)K7 * 4);
    int*   offsb = (int*)alloc((size_t)(K7 + 1) * 4);
    int2*  pairEB = (int2*)alloc((size_t)P * 8);
    int*   perm  = (int*)alloc((size_t)P * 4);
    float* h1    = (float*)alloc((size_t)N * 128 * 4);
    float* h3    = (float*)alloc((size_t)N * 128 * 4);
    float* h6    = (float*)alloc((size_t)N * 64 * 4);
    float* h7    = (float*)alloc((size_t)N * 13 * 4);
    u16*   xbf1  = (u16*)alloc((size_t)N * 32 * 2);
    u16*   hbf1  = (u16*)alloc((size_t)N * 128 * 2);
    u16*   hbf3  = (u16*)alloc((size_t)N * 128 * 2);
    u16*   hbf6  = (u16*)alloc((size_t)N * 64 * 2);
    u16*   mpart = (u16*)alloc((size_t)P * 128 * 2);  // 256 MiB

    dim3 blk(256);
    dim3 egrid((E + 255) / 256);
    dim3 pgrid((P + 255) / 256);

    // x -> bf16
    tobf_kernel<<<(N * 32 / 4 + 255) / 256, blk, 0, stream>>>(x, xbf1, N * 32 / 4);

    // degree / dst-sorted edge ranks
    zero_kernel<<<(N + 255) / 256, blk, 0, stream>>>(degi, N);
    deg_kernel<<<egrid, blk, 0, stream>>>(dst, degi, E);
    scan_kernel<<<1, 1024, 0, stream>>>(degi, eoff, N);
    erank_kernel<<<egrid, blk, 0, stream>>>(dst, degi, erank, E);

    // ---- ks=3 buckets (layers 1 & 3) ----
    zero_kernel<<<(K3 + 255) / 256, blk, 0, stream>>>(cnt, K3);
    count_kernel<3><<<pgrid, blk, 0, stream>>>(ea, cnt, P);
    scan_kernel<<<1, 1024, 0, stream>>>(cnt, offsb, K3);
    fill_kernel<3><<<pgrid, blk, 0, stream>>>(ea, cnt, erank, pairEB, perm, P);

    // layer 1: 32 -> 128
    conv_mfma_r<32, 128, 2, 2, 8><<<dim3(K3, 8), blk, 0, stream>>>(
        xbf1, src, W1, offsb, pairEB, mpart);
    reduce_mfma<32, 128, 128><<<N, blk, 0, stream>>>(mpart, perm, eoff, x, Wr1, b1, h1, hbf1, N);

    // layer 3: 128 -> 128
    conv_mfma_r<128, 128, 2, 2, 8><<<dim3(K3, 8), blk, 0, stream>>>(
        hbf1, src, W3, offsb, pairEB, mpart);
    reduce_mfma<128, 128, 128><<<N, blk, 0, stream>>>(mpart, perm, eoff, h1, Wr3, b3, h3, hbf3, N);

    // ---- ks=5 buckets ----
    zero_kernel<<<(K5 + 255) / 256, blk, 0, stream>>>(cnt, K5);
    count_kernel<5><<<pgrid, blk, 0, stream>>>(ea, cnt, P);
    scan_kernel<<<1, 1024, 0, stream>>>(cnt, offsb, K5);
    fill_kernel<5><<<pgrid, blk, 0, stream>>>(ea, cnt, erank, pairEB, perm, P);

    // layer 6: 128 -> 64
    conv_mfma_r<128, 64, 2, 2, 1><<<dim3(K5, 1), blk, 0, stream>>>(
        hbf3, src, W6, offsb, pairEB, mpart);
    reduce_mfma<128, 64, 64><<<N, blk, 0, stream>>>(mpart, perm, eoff, h3, Wr6, b6, h6, hbf6, N);

    // ---- ks=7 buckets ----
    zero_kernel<<<(K7 + 255) / 256, blk, 0, stream>>>(cnt, K7);
    count_kernel<7><<<pgrid, blk, 0, stream>>>(ea, cnt, P);
    scan_kernel<<<1, 1024, 0, stream>>>(cnt, offsb, K7);
    fill_kernel<7><<<pgrid, blk, 0, stream>>>(ea, cnt, erank, pairEB, perm, P);

    // layer 7: 64 -> 13 (wave per bucket)
    conv_mfma_w7<<<(K7 + 3) / 4, blk, 0, stream>>>(hbf6, src, W7, offsb, pairEB, mpart, K7);
    reduce_mfma<64, 13, 16><<<N, blk, 0, stream>>>(mpart, perm, eoff, h6, Wr7, b7, h7, nullptr, N);

    // ELU + log_softmax
    head_kernel<<<(N + 255) / 256, blk, 0, stream>>>(h7, (float*)d_out, N);
}

// Round 6
// 1570.074 us; speedup vs baseline: 5.9931x; 1.1093x over previous
//
#include <hip/hip_runtime.h>
#include <hip/hip_bf16.h>
#include <cstdint>
#include <cstddef>

constexpr int SDIM = 6;
constexpr int SCOR = 64;   // 2^6 corners
typedef unsigned short u16;
typedef __attribute__((ext_vector_type(8))) short bf16x8;
typedef __attribute__((ext_vector_type(4))) float f32x4;

__device__ __forceinline__ float bf2f(u16 h) {
    union { unsigned u; float f; } v; v.u = ((unsigned)h) << 16; return v.f;
}
__device__ __forceinline__ u16 f2bf(float f) {
    union { float f; unsigned u; } v; v.f = f;
    unsigned r = v.u + 0x7fffu + ((v.u >> 16) & 1u);
    return (u16)(r >> 16);
}

// key+basis for one (edge-coords u[6], corner s) at kernel size KS
template <int KS>
__device__ __forceinline__ void keybasis(const float* u, int s, int& key, float& basis) {
    int idx = 0, str = 1;
    float b = 1.0f;
    #pragma unroll
    for (int d = 0; d < SDIM; d++) {
        float v = u[d] * (KS - 1);
        float fl = floorf(v);
        float fr = v - fl;
        int bit = (s >> d) & 1;
        int pos = (int)fl + bit;
        pos = min(max(pos, 0), KS - 1);
        idx += pos * str;
        str *= KS;
        b *= bit ? fr : (1.0f - fr);
    }
    key = idx;
    basis = b;
}

// ---------------- zero helper ----------------
__global__ __launch_bounds__(256) void zero_kernel(int* __restrict__ p, int n) {
    int i = blockIdx.x * blockDim.x + threadIdx.x;
    if (i < n) p[i] = 0;
}

// ---------------- fp32 -> bf16 convert ----------------
__global__ __launch_bounds__(256) void tobf_kernel(const float* __restrict__ in,
                                                   u16* __restrict__ out, int n4) {
    int i = blockIdx.x * blockDim.x + threadIdx.x;
    if (i < n4) {
        float4 v = ((const float4*)in)[i];
        ushort4 o;
        o.x = f2bf(v.x); o.y = f2bf(v.y); o.z = f2bf(v.z); o.w = f2bf(v.w);
        ((ushort4*)out)[i] = o;
    }
}

// ---------------- fused counting: 3 kernel sizes + degree ----------------
__global__ __launch_bounds__(256) void count_all(const float* __restrict__ ea,
                                                 const int* __restrict__ dst,
                                                 int* __restrict__ cnt3,
                                                 int* __restrict__ cnt5,
                                                 int* __restrict__ cnt7,
                                                 int* __restrict__ degi, int P) {
    int gid = blockIdx.x * blockDim.x + threadIdx.x;
    if (gid >= P) return;
    int e = gid >> 6, s = gid & 63;
    float u[SDIM];
    #pragma unroll
    for (int d = 0; d < SDIM; d++) u[d] = ea[e * SDIM + d];
    int k; float b;
    keybasis<3>(u, s, k, b); atomicAdd(&cnt3[k], 1);
    keybasis<5>(u, s, k, b); atomicAdd(&cnt5[k], 1);
    keybasis<7>(u, s, k, b); atomicAdd(&cnt7[k], 1);
    if (s == 0) atomicAdd(&degi[dst[e]], 1);
}

__global__ __launch_bounds__(256) void erank_kernel(const int* __restrict__ dst,
                                                    int* __restrict__ cursor,
                                                    int* __restrict__ erank, int E) {
    int e = blockIdx.x * blockDim.x + threadIdx.x;
    if (e < E) erank[e] = atomicAdd(&cursor[dst[e]], 1);
}

// ---------------- fused fill: place pair into all 3 bucket structures ----------------
__global__ __launch_bounds__(256) void fill_all(const float* __restrict__ ea,
                                                const int* __restrict__ erank,
                                                int* __restrict__ cur3, int2* __restrict__ pEB3, int* __restrict__ perm3,
                                                int* __restrict__ cur5, int2* __restrict__ pEB5, int* __restrict__ perm5,
                                                int* __restrict__ cur7, int2* __restrict__ pEB7, int* __restrict__ perm7,
                                                int P) {
    int gid = blockIdx.x * blockDim.x + threadIdx.x;
    if (gid >= P) return;
    int e = gid >> 6, s = gid & 63;
    float u[SDIM];
    #pragma unroll
    for (int d = 0; d < SDIM; d++) u[d] = ea[e * SDIM + d];
    int er64 = erank[e] * SCOR + s;
    int k; float b; int slot; int2 eb; eb.x = e;
    keybasis<3>(u, s, k, b);
    slot = atomicAdd(&cur3[k], 1);
    eb.y = __float_as_int(b); pEB3[slot] = eb; perm3[er64] = slot;
    keybasis<5>(u, s, k, b);
    slot = atomicAdd(&cur5[k], 1);
    eb.y = __float_as_int(b); pEB5[slot] = eb; perm5[er64] = slot;
    keybasis<7>(u, s, k, b);
    slot = atomicAdd(&cur7[k], 1);
    eb.y = __float_as_int(b); pEB7[slot] = eb; perm7[er64] = slot;
}

// single-block exclusive scan; counts becomes the fill cursor (= offs)
__global__ __launch_bounds__(1024) void scan_kernel(int* __restrict__ counts,
                                                    int* __restrict__ offs, int K) {
    __shared__ int sums[1024];
    int t = threadIdx.x;
    int chunk = (K + 1023) / 1024;
    int a0 = t * chunk;
    int a1 = min(a0 + chunk, K);
    int s = 0;
    for (int j = a0; j < a1; j++) s += counts[j];
    sums[t] = s;
    __syncthreads();
    for (int off = 1; off < 1024; off <<= 1) {
        int v = (t >= off) ? sums[t - off] : 0;
        __syncthreads();
        sums[t] += v;
        __syncthreads();
    }
    int run = (t == 0) ? 0 : sums[t - 1];
    for (int j = a0; j < a1; j++) {
        int c = counts[j];
        offs[j] = run;
        counts[j] = run;  // cursor init
        run += c;
    }
    if (t == 1023) offs[K] = run;
}

// ---------------- MFMA bucketed conv, B-fragments in registers ----------------
template <int IN, int OUT, int WM, int WN, int GY>
__global__ __launch_bounds__(WM * WN * 64) void conv_mfma_r(
    const u16* __restrict__ xbf, const int* __restrict__ src,
    const float* __restrict__ W, const int* __restrict__ offs,
    const int2* __restrict__ pairEB, u16* __restrict__ mpart) {
    constexpr int NT = WM * WN * 64;
    constexpr int OUT16 = (OUT + 15) & ~15;
    constexpr int NF = OUT16 / 16;   // total col-frags
    constexpr int NFW = NF / WN;     // col-frags per wave
    constexpr int MT = WM * 16;      // pairs per tile
    constexpr int KS = IN / 32;      // k-steps
    constexpr int STR = OUT16 + 8;   // tbuf stride (u16), 16B-aligned rows
    constexpr int CH = OUT16 / 8;    // 16B chunks per row

    __shared__ u16 tbuf[MT * STR];
    __shared__ int sE[MT];
    __shared__ float bas[MT];

    int k = blockIdx.x;
    int p0 = offs[k], p1 = offs[k + 1];
    if (p0 + MT * (int)blockIdx.y >= p1) return;

    int t = threadIdx.x;
    int wid = t >> 6, lane = t & 63;
    int wm = wid % WM, wn = wid / WM;
    int l15 = lane & 15, l4 = lane >> 4;

    // gather B fragments into registers (once per block)
    const float* Wg = W + (size_t)k * IN * OUT;
    bf16x8 breg[KS][NFW];
    #pragma unroll
    for (int ks = 0; ks < KS; ks++) {
        #pragma unroll
        for (int nf = 0; nf < NFW; nf++) {
            int col = (wn * NFW + nf) * 16 + l15;
            bool ok = (OUT == OUT16) || (col < OUT);
            int rbase = ks * 32 + l4 * 8;
            bf16x8 b;
            #pragma unroll
            for (int j = 0; j < 8; j++) {
                float v = ok ? Wg[(rbase + j) * OUT + col] : 0.0f;
                ((u16*)&b)[j] = f2bf(v);
            }
            breg[ks][nf] = b;
        }
    }

    for (int t0 = p0 + MT * blockIdx.y; t0 < p1; t0 += MT * GY) {
        int np = min(MT, p1 - t0);
        if (t < MT) {
            int pp = t0 + t;
            if (pp < p1) {
                int2 eb = pairEB[pp];
                sE[t] = src[eb.x];
                bas[t] = __int_as_float(eb.y);
            } else {
                sE[t] = 0;
                bas[t] = 0.0f;
            }
        }
        __syncthreads();

        int prow = wm * 16 + l15;
        int node = sE[prow < np ? prow : 0];
        const u16* xrow = xbf + (size_t)node * IN + l4 * 8;

        f32x4 acc[NFW];
        #pragma unroll
        for (int nf = 0; nf < NFW; nf++)
            acc[nf] = f32x4{0.f, 0.f, 0.f, 0.f};

        #pragma unroll
        for (int ks = 0; ks < KS; ks++) {
            bf16x8 a = *(const bf16x8*)(xrow + ks * 32);
            #pragma unroll
            for (int nf = 0; nf < NFW; nf++)
                acc[nf] = __builtin_amdgcn_mfma_f32_16x16x32_bf16(a, breg[ks][nf], acc[nf], 0, 0, 0);
        }

        // scale by basis, transpose via LDS
        #pragma unroll
        for (int nf = 0; nf < NFW; nf++) {
            int col = (wn * NFW + nf) * 16 + l15;
            #pragma unroll
            for (int r = 0; r < 4; r++) {
                int pl = wm * 16 + l4 * 4 + r;
                tbuf[pl * STR + col] = f2bf(acc[nf][r] * bas[pl]);
            }
        }
        __syncthreads();

        // coalesced store: np rows of OUT16 bf16 to mpart (bucket-slot order)
        for (int idx = t; idx < np * CH; idx += NT) {
            int row = idx / CH, ch = idx % CH;
            *(bf16x8*)(mpart + (size_t)(t0 + row) * OUT16 + ch * 8) =
                *(const bf16x8*)&tbuf[row * STR + ch * 8];
        }
        __syncthreads();
    }
}

// ---------------- wave-per-bucket conv for ks=7 (IN=64, OUT=13), reg B ----------------
__global__ __launch_bounds__(256) void conv_mfma_w7(
    const u16* __restrict__ xbf, const int* __restrict__ src,
    const float* __restrict__ W, const int* __restrict__ offs,
    const int2* __restrict__ pairEB, u16* __restrict__ mpart, int K) {
    constexpr int IN = 64, OUT = 13, OUT16 = 16;
    __shared__ u16 tbAll[4][16 * 24];
    int t = threadIdx.x, wid = t >> 6, lane = t & 63;
    int k = blockIdx.x * 4 + wid;
    if (k >= K) return;
    int p0 = offs[k], p1 = offs[k + 1];
    if (p0 >= p1) return;
    u16* tb = tbAll[wid];

    int l15 = lane & 15, l4 = lane >> 4;
    const float* Wg = W + (size_t)k * (IN * OUT);
    bf16x8 breg[2];
    #pragma unroll
    for (int ks = 0; ks < 2; ks++) {
        bf16x8 b;
        int rbase = ks * 32 + l4 * 8;
        #pragma unroll
        for (int j = 0; j < 8; j++) {
            float v = (l15 < OUT) ? Wg[(rbase + j) * OUT + l15] : 0.0f;
            ((u16*)&b)[j] = f2bf(v);
        }
        breg[ks] = b;
    }

    for (int t0 = p0; t0 < p1; t0 += 16) {
        int np = min(16, p1 - t0);
        int pr = (l15 < np) ? l15 : 0;
        int node = src[pairEB[t0 + pr].x];
        const u16* xrow = xbf + (size_t)node * IN + l4 * 8;
        f32x4 acc = f32x4{0.f, 0.f, 0.f, 0.f};
        #pragma unroll
        for (int ks = 0; ks < 2; ks++) {
            bf16x8 a = *(const bf16x8*)(xrow + ks * 32);
            acc = __builtin_amdgcn_mfma_f32_16x16x32_bf16(a, breg[ks], acc, 0, 0, 0);
        }
        #pragma unroll
        for (int r = 0; r < 4; r++) {
            int pl = l4 * 4 + r;
            float bsv = (pl < np) ? __int_as_float(pairEB[t0 + pl].y) : 0.0f;
            tb[pl * 24 + l15] = f2bf(acc[r] * bsv);
        }
        if (lane < np * 2) {
            int row = lane >> 1, ch = lane & 1;
            *(bf16x8*)(mpart + (size_t)(t0 + row) * OUT16 + ch * 8) =
                *(const bf16x8*)&tb[row * 24 + ch * 8];
        }
    }
}

// ---------------- gather segment reduce + mean + root + bias ----------------
template <int IN, int OUT, int OUT16>
__global__ __launch_bounds__(256) void reduce_mfma(
    const u16* __restrict__ mpart, const int* __restrict__ perm,
    const int* __restrict__ eoff, const float* __restrict__ xin,
    const float* __restrict__ Wr, const float* __restrict__ bias,
    float* __restrict__ hout, u16* __restrict__ hbf, int N) {
    int n = blockIdx.x;
    int e0 = eoff[n], e1 = eoff[n + 1];
    int R = (e1 - e0) * SCOR;
    size_t rs = (size_t)e0 * SCOR;
    constexpr int CH = OUT16 / 8;
    constexpr int G = 256 / CH;
    int t = threadIdx.x;
    int ch = t % CH, rg = t / CH;
    float a[8] = {0, 0, 0, 0, 0, 0, 0, 0};
    #pragma unroll 4
    for (int r = rg; r < R; r += G) {
        int slot = perm[rs + r];
        const u16* mp = mpart + (size_t)slot * OUT16 + ch * 8;
        bf16x8 v = *(const bf16x8*)mp;
        #pragma unroll
        for (int j = 0; j < 8; j++) a[j] += bf2f(((const u16*)&v)[j]);
    }
    __shared__ float part[256 * 9];
    #pragma unroll
    for (int j = 0; j < 8; j++) part[t * 9 + j] = a[j];
    __syncthreads();
    for (int h = G / 2; h >= 1; h >>= 1) {
        if (rg < h) {
            #pragma unroll
            for (int j = 0; j < 8; j++)
                part[t * 9 + j] += part[(t + h * CH) * 9 + j];
        }
        __syncthreads();
    }
    if (t < OUT) {
        int och = t / 8, oj = t % 8;
        float s = part[och * 9 + oj];
        int dg = e1 - e0;
        s /= (dg < 1) ? 1.0f : (float)dg;
        s += bias[t];
        const float* xr = xin + (size_t)n * IN;
        #pragma unroll 8
        for (int i = 0; i < IN; i++) s += xr[i] * Wr[i * OUT + t];
        hout[(size_t)n * OUT + t] = s;
        if (hbf) hbf[(size_t)n * OUT + t] = f2bf(s);
    }
}

// ---------------- final reduce + ELU + log_softmax fused (layer 7) ----------------
__global__ __launch_bounds__(256) void reduce_head(
    const u16* __restrict__ mpart, const int* __restrict__ perm,
    const int* __restrict__ eoff, const float* __restrict__ xin,
    const float* __restrict__ Wr, const float* __restrict__ bias,
    float* __restrict__ out, int N) {
    constexpr int IN = 64, OUT = 13, OUT16 = 16;
    int n = blockIdx.x;
    int e0 = eoff[n], e1 = eoff[n + 1];
    int R = (e1 - e0) * SCOR;
    size_t rs = (size_t)e0 * SCOR;
    constexpr int CH = OUT16 / 8;
    constexpr int G = 256 / CH;
    int t = threadIdx.x;
    int ch = t % CH, rg = t / CH;
    float a[8] = {0, 0, 0, 0, 0, 0, 0, 0};
    #pragma unroll 4
    for (int r = rg; r < R; r += G) {
        int slot = perm[rs + r];
        const u16* mp = mpart + (size_t)slot * OUT16 + ch * 8;
        bf16x8 v = *(const bf16x8*)mp;
        #pragma unroll
        for (int j = 0; j < 8; j++) a[j] += bf2f(((const u16*)&v)[j]);
    }
    __shared__ float part[256 * 9];
    __shared__ float sm[16];
    #pragma unroll
    for (int j = 0; j < 8; j++) part[t * 9 + j] = a[j];
    __syncthreads();
    for (int h = G / 2; h >= 1; h >>= 1) {
        if (rg < h) {
            #pragma unroll
            for (int j = 0; j < 8; j++)
                part[t * 9 + j] += part[(t + h * CH) * 9 + j];
        }
        __syncthreads();
    }
    if (t < OUT) {
        int och = t / 8, oj = t % 8;
        float s = part[och * 9 + oj];
        int dg = e1 - e0;
        s /= (dg < 1) ? 1.0f : (float)dg;
        s += bias[t];
        const float* xr = xin + (size_t)n * IN;
        #pragma unroll 8
        for (int i = 0; i < IN; i++) s += xr[i] * Wr[i * OUT + t];
        sm[t] = s;
    }
    __syncthreads();
    if (t < OUT) {
        float v[13];
        float mx = -1e30f;
        #pragma unroll
        for (int c = 0; c < 13; c++) {
            float z = sm[c];
            z = z > 0.0f ? z : (expf(z) - 1.0f);
            v[c] = z;
            mx = fmaxf(mx, z);
        }
        float sum = 0.0f;
        #pragma unroll
        for (int c = 0; c < 13; c++) sum += expf(v[c] - mx);
        float lse = mx + logf(sum);
        out[(size_t)n * 13 + t] = v[t] - lse;
    }
}

extern "C" void kernel_launch(void* const* d_in, const int* in_sizes, int n_in,
                              void* d_out, int out_size, void* d_ws, size_t ws_size,
                              hipStream_t stream) {
    const float* x   = (const float*)d_in[0];
    const int*   ei  = (const int*)d_in[1];
    const float* ea  = (const float*)d_in[2];
    const float* W1  = (const float*)d_in[3];
    const float* Wr1 = (const float*)d_in[4];
    const float* b1  = (const float*)d_in[5];
    const float* W3  = (const float*)d_in[6];
    const float* Wr3 = (const float*)d_in[7];
    const float* b3  = (const float*)d_in[8];
    const float* W6  = (const float*)d_in[9];
    const float* Wr6 = (const float*)d_in[10];
    const float* b6  = (const float*)d_in[11];
    const float* W7  = (const float*)d_in[12];
    const float* Wr7 = (const float*)d_in[13];
    const float* b7  = (const float*)d_in[14];

    const int N = in_sizes[0] / 32;
    const int E = in_sizes[1] / 2;
    const int* src = ei;
    const int* dst = ei + E;
    (void)n_in; (void)out_size; (void)ws_size;

    const int K3 = 729, K5 = 15625, K7 = 117649;
    const int P = E * SCOR;

    char* ws = (char*)d_ws;
    size_t off = 0;
    auto alloc = [&](size_t bytes) {
        void* p = ws + off;
        off += (bytes + 255) & ~(size_t)255;
        return p;
    };
    // contiguous zeroed block: degi | cnt3 | cnt5 | cnt7
    int*   zb    = (int*)alloc((size_t)(N + K3 + K5 + K7) * 4);
    int*   degi  = zb;
    int*   cnt3  = zb + N;
    int*   cnt5  = cnt3 + K3;
    int*   cnt7  = cnt5 + K5;
    int*   eoff  = (int*)alloc((size_t)(N + 1) * 4);
    int*   erank = (int*)alloc((size_t)E * 4);
    int*   offs3 = (int*)alloc((size_t)(K3 + 1) * 4);
    int*   offs5 = (int*)alloc((size_t)(K5 + 1) * 4);
    int*   offs7 = (int*)alloc((size_t)(K7 + 1) * 4);
    int2*  pEB3  = (int2*)alloc((size_t)P * 8);
    int2*  pEB5  = (int2*)alloc((size_t)P * 8);
    int2*  pEB7  = (int2*)alloc((size_t)P * 8);
    int*   perm3 = (int*)alloc((size_t)P * 4);
    int*   perm5 = (int*)alloc((size_t)P * 4);
    int*   perm7 = (int*)alloc((size_t)P * 4);
    float* h1    = (float*)alloc((size_t)N * 128 * 4);
    float* h3    = (float*)alloc((size_t)N * 128 * 4);
    float* h6    = (float*)alloc((size_t)N * 64 * 4);
    u16*   xbf1  = (u16*)alloc((size_t)N * 32 * 2);
    u16*   hbf1  = (u16*)alloc((size_t)N * 128 * 2);
    u16*   hbf3  = (u16*)alloc((size_t)N * 128 * 2);
    u16*   hbf6  = (u16*)alloc((size_t)N * 64 * 2);
    u16*   mpart = (u16*)alloc((size_t)P * 128 * 2);  // 256 MiB

    dim3 blk(256);
    dim3 egrid((E + 255) / 256);
    dim3 pgrid((P + 255) / 256);

    // zero counters + x -> bf16
    zero_kernel<<<(N + K3 + K5 + K7 + 255) / 256, blk, 0, stream>>>(zb, N + K3 + K5 + K7);
    tobf_kernel<<<(N * 32 / 4 + 255) / 256, blk, 0, stream>>>(x, xbf1, N * 32 / 4);

    // fused counting (3 ks + degree)
    count_all<<<pgrid, blk, 0, stream>>>(ea, dst, cnt3, cnt5, cnt7, degi, P);

    // scans (cursor-init counts) + edge ranks
    scan_kernel<<<1, 1024, 0, stream>>>(degi, eoff, N);
    erank_kernel<<<egrid, blk, 0, stream>>>(dst, degi, erank, E);
    scan_kernel<<<1, 1024, 0, stream>>>(cnt3, offs3, K3);
    scan_kernel<<<1, 1024, 0, stream>>>(cnt5, offs5, K5);
    scan_kernel<<<1, 1024, 0, stream>>>(cnt7, offs7, K7);

    // fused fill (3 ks in one pass)
    fill_all<<<pgrid, blk, 0, stream>>>(ea, erank,
                                        cnt3, pEB3, perm3,
                                        cnt5, pEB5, perm5,
                                        cnt7, pEB7, perm7, P);

    // layer 1: 32 -> 128 (512-thread blocks, MT=64)
    conv_mfma_r<32, 128, 4, 2, 4><<<dim3(K3, 4), dim3(512), 0, stream>>>(
        xbf1, src, W1, offs3, pEB3, mpart);
    reduce_mfma<32, 128, 128><<<N, blk, 0, stream>>>(mpart, perm3, eoff, x, Wr1, b1, h1, hbf1, N);

    // layer 3: 128 -> 128
    conv_mfma_r<128, 128, 4, 2, 8><<<dim3(K3, 8), dim3(512), 0, stream>>>(
        hbf1, src, W3, offs3, pEB3, mpart);
    reduce_mfma<128, 128, 128><<<N, blk, 0, stream>>>(mpart, perm3, eoff, h1, Wr3, b3, h3, hbf3, N);

    // layer 6: 128 -> 64
    conv_mfma_r<128, 64, 2, 2, 1><<<dim3(K5, 1), blk, 0, stream>>>(
        hbf3, src, W6, offs5, pEB5, mpart);
    reduce_mfma<128, 64, 64><<<N, blk, 0, stream>>>(mpart, perm5, eoff, h3, Wr6, b6, h6, hbf6, N);

    // layer 7: 64 -> 13 (wave per bucket) + fused head
    conv_mfma_w7<<<(K7 + 3) / 4, blk, 0, stream>>>(hbf6, src, W7, offs7, pEB7, mpart, K7);
    reduce_head<<<N, blk, 0, stream>>>(mpart, perm7, eoff, h6, Wr7, b7, (float*)d_out, N);
}

// Round 7
// 1355.369 us; speedup vs baseline: 6.9425x; 1.1584x over previous
//
#include <hip/hip_runtime.h>
#include <hip/hip_bf16.h>
#include <cstdint>
#include <cstddef>

constexpr int SDIM = 6;
constexpr int SCOR = 64;   // 2^6 corners
typedef unsigned short u16;
typedef __attribute__((ext_vector_type(8))) short bf16x8;
typedef __attribute__((ext_vector_type(4))) float f32x4;

__device__ __forceinline__ float bf2f(u16 h) {
    union { unsigned u; float f; } v; v.u = ((unsigned)h) << 16; return v.f;
}
__device__ __forceinline__ u16 f2bf(float f) {
    union { float f; unsigned u; } v; v.f = f;
    unsigned r = v.u + 0x7fffu + ((v.u >> 16) & 1u);
    return (u16)(r >> 16);
}

template <int KS>
__device__ __forceinline__ void keybasis(const float* u, int s, int& key, float& basis) {
    int idx = 0, str = 1;
    float b = 1.0f;
    #pragma unroll
    for (int d = 0; d < SDIM; d++) {
        float v = u[d] * (KS - 1);
        float fl = floorf(v);
        float fr = v - fl;
        int bit = (s >> d) & 1;
        int pos = (int)fl + bit;
        pos = min(max(pos, 0), KS - 1);
        idx += pos * str;
        str *= KS;
        b *= bit ? fr : (1.0f - fr);
    }
    key = idx;
    basis = b;
}

// ---------------- zero helper ----------------
__global__ __launch_bounds__(256) void zero_kernel(int* __restrict__ p, int n) {
    int i = blockIdx.x * blockDim.x + threadIdx.x;
    if (i < n) p[i] = 0;
}

// ---------------- fp32 -> bf16 convert ----------------
__global__ __launch_bounds__(256) void tobf_kernel(const float* __restrict__ in,
                                                   u16* __restrict__ out, int n4) {
    int i = blockIdx.x * blockDim.x + threadIdx.x;
    if (i < n4) {
        float4 v = ((const float4*)in)[i];
        ushort4 o;
        o.x = f2bf(v.x); o.y = f2bf(v.y); o.z = f2bf(v.z); o.w = f2bf(v.w);
        ((ushort4*)out)[i] = o;
    }
}

// ---------------- fused counting: 3 kernel sizes + degree ----------------
__global__ __launch_bounds__(256) void count_all(const float* __restrict__ ea,
                                                 const int* __restrict__ dst,
                                                 int* __restrict__ cnt3,
                                                 int* __restrict__ cnt5,
                                                 int* __restrict__ cnt7,
                                                 int* __restrict__ degi, int P) {
    int gid = blockIdx.x * blockDim.x + threadIdx.x;
    if (gid >= P) return;
    int e = gid >> 6, s = gid & 63;
    float u[SDIM];
    #pragma unroll
    for (int d = 0; d < SDIM; d++) u[d] = ea[e * SDIM + d];
    int k; float b;
    keybasis<3>(u, s, k, b); atomicAdd(&cnt3[k], 1);
    keybasis<5>(u, s, k, b); atomicAdd(&cnt5[k], 1);
    keybasis<7>(u, s, k, b); atomicAdd(&cnt7[k], 1);
    if (s == 0) atomicAdd(&degi[dst[e]], 1);
}

// ---------------- parallel segmented scan over zb = [deg|cnt3|cnt5|cnt7] ----------------
// zb padded so each segment starts on a 1024-element boundary.
__global__ __launch_bounds__(256) void scan_partial(const int* __restrict__ zb,
                                                    int* __restrict__ bsum) {
    int b = blockIdx.x, t = threadIdx.x;
    int4 v = *(const int4*)(zb + b * 1024 + t * 4);
    __shared__ int red[256];
    red[t] = v.x + v.y + v.z + v.w;
    __syncthreads();
    for (int h = 128; h >= 1; h >>= 1) {
        if (t < h) red[t] += red[t + h];
        __syncthreads();
    }
    if (t == 0) bsum[b] = red[0];
}

__global__ __launch_bounds__(256) void scan_final(int* __restrict__ zb,
                                                  const int* __restrict__ bsum,
                                                  int* __restrict__ eoff,
                                                  int* __restrict__ offs3,
                                                  int* __restrict__ offs5,
                                                  int* __restrict__ offs7,
                                                  int Nn, int nb0) {
    int b = blockIdx.x, t = threadIdx.x;
    int s1 = nb0, s2 = nb0 + 1, s3 = nb0 + 17;
    int seg = (b >= s3) ? 3 : (b >= s2) ? 2 : (b >= s1) ? 1 : 0;
    int sb = (seg == 0) ? 0 : (seg == 1) ? s1 : (seg == 2) ? s2 : s3;
    int L = (seg == 0) ? Nn : (seg == 1) ? 729 : (seg == 2) ? 15625 : 117649;
    int* offs = (seg == 0) ? eoff : (seg == 1) ? offs3 : (seg == 2) ? offs5 : offs7;

    // sum of preceding block-sums within this segment
    __shared__ int red[256];
    int cnt = b - sb;
    int acc = 0;
    for (int j = t; j < cnt; j += 256) acc += bsum[sb + j];
    red[t] = acc;
    __syncthreads();
    for (int h = 128; h >= 1; h >>= 1) {
        if (t < h) red[t] += red[t + h];
        __syncthreads();
    }
    int blockPrefix = red[0];
    __syncthreads();

    int idx = b * 1024 + t * 4;
    int4 v = *(const int4*)(zb + idx);
    int tsum = v.x + v.y + v.z + v.w;
    __shared__ int ss[256];
    ss[t] = tsum;
    __syncthreads();
    for (int off = 1; off < 256; off <<= 1) {
        int val = (t >= off) ? ss[t - off] : 0;
        __syncthreads();
        ss[t] += val;
        __syncthreads();
    }
    int p = blockPrefix + ((t == 0) ? 0 : ss[t - 1]);
    int pe[4];
    pe[0] = p;
    pe[1] = p + v.x;
    pe[2] = pe[1] + v.y;
    pe[3] = pe[2] + v.z;
    int vv[4] = {v.x, v.y, v.z, v.w};
    int li = (b - sb) * 1024 + t * 4;
    #pragma unroll
    for (int j = 0; j < 4; j++) {
        int gi = li + j;
        if (gi < L) {
            offs[gi] = pe[j];
            zb[idx + j] = pe[j];   // cursor init for fill/erank
            if (gi == L - 1) offs[L] = pe[j] + vv[j];
        }
    }
}

__global__ __launch_bounds__(256) void erank_kernel(const int* __restrict__ dst,
                                                    int* __restrict__ cursor,
                                                    int* __restrict__ erank, int E) {
    int e = blockIdx.x * blockDim.x + threadIdx.x;
    if (e < E) erank[e] = atomicAdd(&cursor[dst[e]], 1);
}

// ---------------- fused fill: {e, basis, er64} into 3 bucket structures ----------------
__global__ __launch_bounds__(256) void fill_all(const float* __restrict__ ea,
                                                const int* __restrict__ erank,
                                                int* __restrict__ cur3, int4* __restrict__ pP3,
                                                int* __restrict__ cur5, int4* __restrict__ pP5,
                                                int* __restrict__ cur7, int4* __restrict__ pP7,
                                                int P) {
    int gid = blockIdx.x * blockDim.x + threadIdx.x;
    if (gid >= P) return;
    int e = gid >> 6, s = gid & 63;
    float u[SDIM];
    #pragma unroll
    for (int d = 0; d < SDIM; d++) u[d] = ea[e * SDIM + d];
    int er64 = erank[e] * SCOR + s;
    int k; float b; int slot;
    keybasis<3>(u, s, k, b);
    slot = atomicAdd(&cur3[k], 1);
    pP3[slot] = make_int4(e, __float_as_int(b), er64, 0);
    keybasis<5>(u, s, k, b);
    slot = atomicAdd(&cur5[k], 1);
    pP5[slot] = make_int4(e, __float_as_int(b), er64, 0);
    keybasis<7>(u, s, k, b);
    slot = atomicAdd(&cur7[k], 1);
    pP7[slot] = make_int4(e, __float_as_int(b), er64, 0);
}

// ---------------- MFMA bucketed conv, B in registers, scatter-store at er64 ----------------
template <int IN, int OUT, int WM, int WN, int GY>
__global__ __launch_bounds__(WM * WN * 64) void conv_mfma_r(
    const u16* __restrict__ xbf, const int* __restrict__ src,
    const float* __restrict__ W, const int* __restrict__ offs,
    const int4* __restrict__ pairP, u16* __restrict__ mpart) {
    constexpr int NT = WM * WN * 64;
    constexpr int OUT16 = (OUT + 15) & ~15;
    constexpr int NF = OUT16 / 16;
    constexpr int NFW = NF / WN;
    constexpr int MT = WM * 16;
    constexpr int KS = IN / 32;
    constexpr int STR = OUT16 + 8;
    constexpr int CH = OUT16 / 8;

    __shared__ u16 tbuf[MT * STR];
    __shared__ int sE[MT];
    __shared__ float bas[MT];
    __shared__ int sR[MT];

    int k = blockIdx.x;
    int p0 = offs[k], p1 = offs[k + 1];
    if (p0 + MT * (int)blockIdx.y >= p1) return;

    int t = threadIdx.x;
    int wid = t >> 6, lane = t & 63;
    int wm = wid % WM, wn = wid / WM;
    int l15 = lane & 15, l4 = lane >> 4;

    // gather B fragments into registers (once per block)
    const float* Wg = W + (size_t)k * IN * OUT;
    bf16x8 breg[KS][NFW];
    #pragma unroll
    for (int ks = 0; ks < KS; ks++) {
        #pragma unroll
        for (int nf = 0; nf < NFW; nf++) {
            int col = (wn * NFW + nf) * 16 + l15;
            bool ok = (OUT == OUT16) || (col < OUT);
            int rbase = ks * 32 + l4 * 8;
            bf16x8 b;
            #pragma unroll
            for (int j = 0; j < 8; j++) {
                float v = ok ? Wg[(rbase + j) * OUT + col] : 0.0f;
                ((u16*)&b)[j] = f2bf(v);
            }
            breg[ks][nf] = b;
        }
    }

    for (int t0 = p0 + MT * blockIdx.y; t0 < p1; t0 += MT * GY) {
        int np = min(MT, p1 - t0);
        if (t < MT) {
            int pp = t0 + t;
            if (pp < p1) {
                int4 pr = pairP[pp];
                sE[t] = src[pr.x];
                bas[t] = __int_as_float(pr.y);
                sR[t] = pr.z;
            } else {
                sE[t] = 0;
                bas[t] = 0.0f;
                sR[t] = 0;
            }
        }
        __syncthreads();

        int prow = wm * 16 + l15;
        int node = sE[prow < np ? prow : 0];
        const u16* xrow = xbf + (size_t)node * IN + l4 * 8;

        f32x4 acc[NFW];
        #pragma unroll
        for (int nf = 0; nf < NFW; nf++)
            acc[nf] = f32x4{0.f, 0.f, 0.f, 0.f};

        #pragma unroll
        for (int ks = 0; ks < KS; ks++) {
            bf16x8 a = *(const bf16x8*)(xrow + ks * 32);
            #pragma unroll
            for (int nf = 0; nf < NFW; nf++)
                acc[nf] = __builtin_amdgcn_mfma_f32_16x16x32_bf16(a, breg[ks][nf], acc[nf], 0, 0, 0);
        }

        // scale by basis, transpose via LDS
        #pragma unroll
        for (int nf = 0; nf < NFW; nf++) {
            int col = (wn * NFW + nf) * 16 + l15;
            #pragma unroll
            for (int r = 0; r < 4; r++) {
                int pl = wm * 16 + l4 * 4 + r;
                tbuf[pl * STR + col] = f2bf(acc[nf][r] * bas[pl]);
            }
        }
        __syncthreads();

        // scatter-store rows to dst-sorted position er64
        for (int idx = t; idx < np * CH; idx += NT) {
            int row = idx / CH, ch = idx % CH;
            *(bf16x8*)(mpart + (size_t)sR[row] * OUT16 + ch * 8) =
                *(const bf16x8*)&tbuf[row * STR + ch * 8];
        }
        __syncthreads();
    }
}

// ---------------- wave-per-bucket conv for ks=7 (IN=64, OUT=13) ----------------
__global__ __launch_bounds__(256) void conv_mfma_w7(
    const u16* __restrict__ xbf, const int* __restrict__ src,
    const float* __restrict__ W, const int* __restrict__ offs,
    const int4* __restrict__ pairP, u16* __restrict__ mpart, int K) {
    constexpr int IN = 64, OUT = 13, OUT16 = 16;
    __shared__ u16 WT[4][16 * 72];   // per wave: [col][row] padded
    __shared__ u16 tbAll[4][16 * 24];
    int t = threadIdx.x, wid = t >> 6, lane = t & 63;
    int k = blockIdx.x * 4 + wid;
    if (k >= K) return;
    int p0 = offs[k], p1 = offs[k + 1];
    if (p0 >= p1) return;
    u16* tb = tbAll[wid];
    u16* wt = WT[wid];

    int l15 = lane & 15, l4 = lane >> 4;
    // coalesced W load -> transposed LDS (wave-private, no barrier needed)
    const float* Wg = W + (size_t)k * (IN * OUT);
    for (int f = lane; f < IN * OUT; f += 64) {
        int r = f / OUT, c = f - r * OUT;
        wt[c * 72 + r] = f2bf(Wg[f]);
    }
    bf16x8 breg[2];
    #pragma unroll
    for (int ks = 0; ks < 2; ks++)
        breg[ks] = (l15 < OUT) ? *(const bf16x8*)&wt[l15 * 72 + ks * 32 + l4 * 8]
                               : bf16x8{0, 0, 0, 0, 0, 0, 0, 0};

    for (int t0 = p0; t0 < p1; t0 += 16) {
        int np = min(16, p1 - t0);
        int pr = (l15 < np) ? l15 : 0;
        int node = src[pairP[t0 + pr].x];
        const u16* xrow = xbf + (size_t)node * IN + l4 * 8;
        f32x4 acc = f32x4{0.f, 0.f, 0.f, 0.f};
        #pragma unroll
        for (int ks = 0; ks < 2; ks++) {
            bf16x8 a = *(const bf16x8*)(xrow + ks * 32);
            acc = __builtin_amdgcn_mfma_f32_16x16x32_bf16(a, breg[ks], acc, 0, 0, 0);
        }
        #pragma unroll
        for (int r = 0; r < 4; r++) {
            int pl = l4 * 4 + r;
            float bsv = (pl < np) ? __int_as_float(pairP[t0 + pl].y) : 0.0f;
            tb[pl * 24 + l15] = f2bf(acc[r] * bsv);
        }
        if (lane < np * 2) {
            int row = lane >> 1, ch = lane & 1;
            size_t dr = (size_t)pairP[t0 + row].z;
            *(bf16x8*)(mpart + dr * OUT16 + ch * 8) =
                *(const bf16x8*)&tb[row * 24 + ch * 8];
        }
    }
}

// ---------------- streaming segment reduce + mean + root + bias ----------------
template <int IN, int OUT, int OUT16>
__global__ __launch_bounds__(256) void reduce_mfma(
    const u16* __restrict__ mpart, const int* __restrict__ eoff,
    const float* __restrict__ xin, const float* __restrict__ Wr,
    const float* __restrict__ bias, float* __restrict__ hout,
    u16* __restrict__ hbf, int N) {
    int n = blockIdx.x;
    int e0 = eoff[n], e1 = eoff[n + 1];
    int R = (e1 - e0) * SCOR;
    size_t rs = (size_t)e0 * SCOR;
    constexpr int CH = OUT16 / 8;
    constexpr int G = 256 / CH;
    int t = threadIdx.x;
    int ch = t % CH, rg = t / CH;
    float a[8] = {0, 0, 0, 0, 0, 0, 0, 0};
    #pragma unroll 4
    for (int r = rg; r < R; r += G) {
        bf16x8 v = *(const bf16x8*)(mpart + (rs + r) * OUT16 + ch * 8);
        #pragma unroll
        for (int j = 0; j < 8; j++) a[j] += bf2f(((const u16*)&v)[j]);
    }
    __shared__ float part[256 * 9];
    #pragma unroll
    for (int j = 0; j < 8; j++) part[t * 9 + j] = a[j];
    __syncthreads();
    for (int h = G / 2; h >= 1; h >>= 1) {
        if (rg < h) {
            #pragma unroll
            for (int j = 0; j < 8; j++)
                part[t * 9 + j] += part[(t + h * CH) * 9 + j];
        }
        __syncthreads();
    }
    if (t < OUT) {
        int och = t / 8, oj = t % 8;
        float s = part[och * 9 + oj];
        int dg = e1 - e0;
        s /= (dg < 1) ? 1.0f : (float)dg;
        s += bias[t];
        const float* xr = xin + (size_t)n * IN;
        #pragma unroll 8
        for (int i = 0; i < IN; i++) s += xr[i] * Wr[i * OUT + t];
        hout[(size_t)n * OUT + t] = s;
        if (hbf) hbf[(size_t)n * OUT + t] = f2bf(s);
    }
}

// ---------------- final reduce + ELU + log_softmax fused (layer 7) ----------------
__global__ __launch_bounds__(256) void reduce_head(
    const u16* __restrict__ mpart, const int* __restrict__ eoff,
    const float* __restrict__ xin, const float* __restrict__ Wr,
    const float* __restrict__ bias, float* __restrict__ out, int N) {
    constexpr int IN = 64, OUT = 13, OUT16 = 16;
    int n = blockIdx.x;
    int e0 = eoff[n], e1 = eoff[n + 1];
    int R = (e1 - e0) * SCOR;
    size_t rs = (size_t)e0 * SCOR;
    constexpr int CH = OUT16 / 8;
    constexpr int G = 256 / CH;
    int t = threadIdx.x;
    int ch = t % CH, rg = t / CH;
    float a[8] = {0, 0, 0, 0, 0, 0, 0, 0};
    #pragma unroll 4
    for (int r = rg; r < R; r += G) {
        bf16x8 v = *(const bf16x8*)(mpart + (rs + r) * OUT16 + ch * 8);
        #pragma unroll
        for (int j = 0; j < 8; j++) a[j] += bf2f(((const u16*)&v)[j]);
    }
    __shared__ float part[256 * 9];
    __shared__ float sm[16];
    #pragma unroll
    for (int j = 0; j < 8; j++) part[t * 9 + j] = a[j];
    __syncthreads();
    for (int h = G / 2; h >= 1; h >>= 1) {
        if (rg < h) {
            #pragma unroll
            for (int j = 0; j < 8; j++)
                part[t * 9 + j] += part[(t + h * CH) * 9 + j];
        }
        __syncthreads();
    }
    if (t < OUT) {
        int och = t / 8, oj = t % 8;
        float s = part[och * 9 + oj];
        int dg = e1 - e0;
        s /= (dg < 1) ? 1.0f : (float)dg;
        s += bias[t];
        const float* xr = xin + (size_t)n * IN;
        #pragma unroll 8
        for (int i = 0; i < IN; i++) s += xr[i] * Wr[i * OUT + t];
        sm[t] = s;
    }
    __syncthreads();
    if (t < OUT) {
        float v[13];
        float mx = -1e30f;
        #pragma unroll
        for (int c = 0; c < 13; c++) {
            float z = sm[c];
            z = z > 0.0f ? z : (expf(z) - 1.0f);
            v[c] = z;
            mx = fmaxf(mx, z);
        }
        float sum = 0.0f;
        #pragma unroll
        for (int c = 0; c < 13; c++) sum += expf(v[c] - mx);
        float lse = mx + logf(sum);
        out[(size_t)n * 13 + t] = v[t] - lse;
    }
}

extern "C" void kernel_launch(void* const* d_in, const int* in_sizes, int n_in,
                              void* d_out, int out_size, void* d_ws, size_t ws_size,
                              hipStream_t stream) {
    const float* x   = (const float*)d_in[0];
    const int*   ei  = (const int*)d_in[1];
    const float* ea  = (const float*)d_in[2];
    const float* W1  = (const float*)d_in[3];
    const float* Wr1 = (const float*)d_in[4];
    const float* b1  = (const float*)d_in[5];
    const float* W3  = (const float*)d_in[6];
    const float* Wr3 = (const float*)d_in[7];
    const float* b3  = (const float*)d_in[8];
    const float* W6  = (const float*)d_in[9];
    const float* Wr6 = (const float*)d_in[10];
    const float* b6  = (const float*)d_in[11];
    const float* W7  = (const float*)d_in[12];
    const float* Wr7 = (const float*)d_in[13];
    const float* b7  = (const float*)d_in[14];

    const int N = in_sizes[0] / 32;
    const int E = in_sizes[1] / 2;
    const int* src = ei;
    const int* dst = ei + E;
    (void)n_in; (void)out_size; (void)ws_size;

    const int K3 = 729, K5 = 15625, K7 = 117649;
    const int P = E * SCOR;

    // padded segment layout for the parallel scan
    const int BS = 1024;
    const int Np = (N + BS - 1) / BS * BS;
    const int nb0 = Np / BS;
    const int P3 = 1024, P5 = 16384, P7 = 117760;   // padded K3/K5/K7
    const int totalPad = Np + P3 + P5 + P7;
    const int nBlocks = nb0 + 1 + 16 + 115;

    char* ws = (char*)d_ws;
    size_t off = 0;
    auto alloc = [&](size_t bytes) {
        void* p = ws + off;
        off += (bytes + 255) & ~(size_t)255;
        return p;
    };
    int*   zb    = (int*)alloc((size_t)totalPad * 4);
    int*   degi  = zb;
    int*   cnt3  = zb + Np;
    int*   cnt5  = cnt3 + P3;
    int*   cnt7  = cnt5 + P5;
    int*   bsum  = (int*)alloc((size_t)nBlocks * 4);
    int*   eoff  = (int*)alloc((size_t)(N + 1) * 4);
    int*   erank = (int*)alloc((size_t)E * 4);
    int*   offs3 = (int*)alloc((size_t)(K3 + 1) * 4);
    int*   offs5 = (int*)alloc((size_t)(K5 + 1) * 4);
    int*   offs7 = (int*)alloc((size_t)(K7 + 1) * 4);
    int4*  pP3   = (int4*)alloc((size_t)P * 16);
    int4*  pP5   = (int4*)alloc((size_t)P * 16);
    int4*  pP7   = (int4*)alloc((size_t)P * 16);
    float* h1    = (float*)alloc((size_t)N * 128 * 4);
    float* h3    = (float*)alloc((size_t)N * 128 * 4);
    float* h6    = (float*)alloc((size_t)N * 64 * 4);
    u16*   xbf1  = (u16*)alloc((size_t)N * 32 * 2);
    u16*   hbf1  = (u16*)alloc((size_t)N * 128 * 2);
    u16*   hbf3  = (u16*)alloc((size_t)N * 128 * 2);
    u16*   hbf6  = (u16*)alloc((size_t)N * 64 * 2);
    u16*   mpart = (u16*)alloc((size_t)P * 128 * 2);  // 256 MiB

    dim3 blk(256);
    dim3 egrid((E + 255) / 256);
    dim3 pgrid((P + 255) / 256);

    // zero counters + x -> bf16
    zero_kernel<<<(totalPad + 255) / 256, blk, 0, stream>>>(zb, totalPad);
    tobf_kernel<<<(N * 32 / 4 + 255) / 256, blk, 0, stream>>>(x, xbf1, N * 32 / 4);

    // fused counting (3 ks + degree)
    count_all<<<pgrid, blk, 0, stream>>>(ea, dst, cnt3, cnt5, cnt7, degi, P);

    // parallel segmented scan: zb -> {eoff, offs3, offs5, offs7}, zb becomes cursors
    scan_partial<<<nBlocks, blk, 0, stream>>>(zb, bsum);
    scan_final<<<nBlocks, blk, 0, stream>>>(zb, bsum, eoff, offs3, offs5, offs7, N, nb0);

    // edge ranks (uses degi cursor)
    erank_kernel<<<egrid, blk, 0, stream>>>(dst, degi, erank, E);

    // fused fill (3 ks in one pass)
    fill_all<<<pgrid, blk, 0, stream>>>(ea, erank, cnt3, pP3, cnt5, pP5, cnt7, pP7, P);

    // layer 1: 32 -> 128
    conv_mfma_r<32, 128, 4, 2, 4><<<dim3(K3, 4), dim3(512), 0, stream>>>(
        xbf1, src, W1, offs3, pP3, mpart);
    reduce_mfma<32, 128, 128><<<N, blk, 0, stream>>>(mpart, eoff, x, Wr1, b1, h1, hbf1, N);

    // layer 3: 128 -> 128
    conv_mfma_r<128, 128, 4, 2, 8><<<dim3(K3, 8), dim3(512), 0, stream>>>(
        hbf1, src, W3, offs3, pP3, mpart);
    reduce_mfma<128, 128, 128><<<N, blk, 0, stream>>>(mpart, eoff, h1, Wr3, b3, h3, hbf3, N);

    // layer 6: 128 -> 64
    conv_mfma_r<128, 64, 2, 2, 1><<<dim3(K5, 1), blk, 0, stream>>>(
        hbf3, src, W6, offs5, pP5, mpart);
    reduce_mfma<128, 64, 64><<<N, blk, 0, stream>>>(mpart, eoff, h3, Wr6, b6, h6, hbf6, N);

    // layer 7: 64 -> 13 (wave per bucket) + fused head
    conv_mfma_w7<<<(K7 + 3) / 4, blk, 0, stream>>>(hbf6, src, W7, offs7, pP7, mpart, K7);
    reduce_head<<<N, blk, 0, stream>>>(mpart, eoff, h6, Wr7, b7, (float*)d_out, N);
}